// Round 9
// baseline (177.526 us; speedup 1.0000x reference)
//
#include <hip/hip_runtime.h>
#include <math.h>

#define B_ 2
#define N_ 2048
#define DIM_ 512
#define H_ 8
#define D_ 64
#define M_ 128
#define NC_ 32
#define C_ 64

#define INV_SQRT_M 0.08838834764831845f
#define QK_SCALE 0.35355339059327373f

typedef __attribute__((ext_vector_type(8))) short bf16x8;
typedef __attribute__((ext_vector_type(4))) short bf16x4;
typedef __attribute__((ext_vector_type(4))) float f32x4;

#define MFMA16(a, b, c) __builtin_amdgcn_mfma_f32_16x16x32_bf16((a), (b), (c), 0, 0, 0)

__device__ __forceinline__ short f2bf(float f) {
    union { float f; unsigned u; } x; x.f = f;
    unsigned r = (x.u + 0x7FFFu + ((x.u >> 16) & 1u)) >> 16;
    return (short)r;
}
__device__ __forceinline__ float bf2f(short s) {
    union { unsigned u; float f; } x; x.u = ((unsigned)(unsigned short)s) << 16;
    return x.f;
}
// monotone float<->uint encoding for atomicMax on floats (incl. negatives)
__device__ __forceinline__ unsigned encf(float f) {
    unsigned u = __float_as_uint(f);
    return (u & 0x80000000u) ? ~u : (u | 0x80000000u);
}
__device__ __forceinline__ float decf(unsigned e) {
    unsigned u = (e & 0x80000000u) ? (e & 0x7FFFFFFFu) : ~e;
    return __uint_as_float(u);
}

// async global->LDS 16B copy: LDS dst = (wave-uniform base) + lane*16
__device__ __forceinline__ void gl16(void* lds, const void* g) {
    __builtin_amdgcn_global_load_lds(
        (const __attribute__((address_space(1))) unsigned int*)g,
        (__attribute__((address_space(3))) unsigned int*)lds,
        16, 0, 0);
}

// fragment load from row-major LDS tile [rows][ldk] bf16 (A or B^T form)
__device__ __forceinline__ bf16x8 ld_frag(const short* base, int row0, int k0, int ldk) {
    const int lane = threadIdx.x & 63;
    return *(const bf16x8*)(base + (row0 + (lane & 15)) * ldk + k0 + ((lane >> 4) << 3));
}

// ---------------- prep (merged): hi/lo x; hi-only Wk/Wv/Wo; omega@W rows; gmax init ----------------
__global__ __launch_bounds__(256) void prep_all(
    const float* __restrict__ x, const float* __restrict__ Wq, const float* __restrict__ Wk,
    const float* __restrict__ Wv, const float* __restrict__ Wo, const float* __restrict__ omega,
    short* __restrict__ xh, short* __restrict__ xl,
    short* __restrict__ Wch, short* __restrict__ Wcl,
    short* __restrict__ Woh, unsigned* __restrict__ gmaxu)
{
    __shared__ float Ws[64][65];
    __shared__ float om[128][64];
    const int t = threadIdx.x;
    const int bid = blockIdx.x;
    if (bid < 2816) {
        int i4 = bid * 256 + t;
        if (i4 == 0) gmaxu[0] = 0u;   // < enc of any real float
        if (i4 < 524288) {
            float4 v = *(const float4*)(x + (size_t)i4 * 4);
            float a[4] = {v.x, v.y, v.z, v.w};
            bf16x4 hi, lo;
            #pragma unroll
            for (int u = 0; u < 4; ++u) {
                short h = f2bf(a[u]); hi[u] = h; lo[u] = f2bf(a[u] - bf2f(h));
            }
            *(bf16x4*)(xh + (size_t)i4 * 4) = hi;
            *(bf16x4*)(xl + (size_t)i4 * 4) = lo;
        } else {
            int r = i4 - 524288;
            int widx = r >> 16, off4 = r & 65535;
            const float* src; short* dst; float sc;
            if (widx == 0)      { src = Wk; dst = Wch;          sc = QK_SCALE; }
            else if (widx == 1) { src = Wv; dst = Wch + 262144; sc = 1.f; }
            else                { src = Wo; dst = Woh;          sc = 1.f; }
            float4 v = *(const float4*)(src + (size_t)off4 * 4);
            bf16x4 hi;
            hi[0] = f2bf(v.x * sc); hi[1] = f2bf(v.y * sc);
            hi[2] = f2bf(v.z * sc); hi[3] = f2bf(v.w * sc);
            *(bf16x4*)(dst + (size_t)off4 * 4) = hi;
        }
    } else {
        // omega @ (W*scale) -> Wcomb rows 1024..3072, hi/lo
        const int bx = bid - 2816;
        const int qk = bx >> 6, h = (bx >> 3) & 7, cb = bx & 7;
        const int col0 = cb * 64;
        const float* W = qk ? Wk : Wq;
        for (int i = t; i < 64 * 64; i += 256) {
            int d = i >> 6, c = i & 63;
            Ws[d][c] = W[(size_t)(h * 64 + d) * 512 + col0 + c] * QK_SCALE;
        }
        for (int i = t; i < 128 * 64; i += 256) om[i >> 6][i & 63] = omega[i];
        __syncthreads();
        const int lane = t & 63, w = t >> 6;
        const int c = col0 + lane;
        float Wcol[64];
        #pragma unroll
        for (int d = 0; d < 64; ++d) Wcol[d] = Ws[d][lane];
        for (int mi = 0; mi < 32; ++mi) {
            int m = w * 32 + mi;
            float acc = 0.f;
            #pragma unroll
            for (int d = 0; d < 64; d += 4) {
                float4 o4 = *(const float4*)&om[m][d];
                acc += o4.x * Wcol[d] + o4.y * Wcol[d+1] + o4.z * Wcol[d+2] + o4.w * Wcol[d+3];
            }
            int row = 1024 + qk * 1024 + h * 128 + m;
            short hi = f2bf(acc);
            Wch[(size_t)row * 512 + c] = hi;
            Wcl[(size_t)row * 512 + c] = f2bf(acc - bf2f(hi));
        }
    }
}

// ---------------- fused GEMM: [4096 x 3072] = x @ Wcomb^T ----------------
// cols [0,512) k->ssq (1-pass); [512,1024) v->bf16 (1-pass);
//      [1024,2048) projq -> phiq bf16 (3-pass, in-epilogue row-max + exp);
//      [2048,3072) projk -> pk_local bf16 + pmaxp (3-pass)
__global__ __launch_bounds__(256) void gemm_fused(
    const short* __restrict__ xh, const short* __restrict__ xl,
    const short* __restrict__ Wch, const short* __restrict__ Wcl,
    short* __restrict__ phiq, short* __restrict__ pkloc,
    short* __restrict__ vbf, float* __restrict__ ssqbuf, float* __restrict__ pmaxp)
{
    __shared__ short Ah[128 * 32];
    __shared__ short Al[128 * 32];
    __shared__ short Bh[128 * 32];
    __shared__ short Bl[128 * 32];
    __shared__ float rmx[128][2];
    const int t = threadIdx.x, lane = t & 63, wave = t >> 6;
    const int wr = wave >> 1, wc = wave & 1;
    const int row0 = blockIdx.x * 128;
    const int by = blockIdx.y;
    const int col0 = by * 128;
    const int l_row = lane >> 2, l_col = (lane & 3) << 3;
    const bool three = (by >= 8);
    f32x4 acc[4][4];
    #pragma unroll
    for (int m = 0; m < 4; ++m)
        #pragma unroll
        for (int n = 0; n < 4; ++n) { f32x4 z = {0.f, 0.f, 0.f, 0.f}; acc[m][n] = z; }
    for (int k0 = 0; k0 < 512; k0 += 32) {
        #pragma unroll
        for (int sub = 0; sub < 2; ++sub) {
            int s = wave * 2 + sub;
            int gr = s * 16 + l_row;
            size_t ga = (size_t)(row0 + gr) * 512 + k0 + l_col;
            size_t gb = (size_t)(col0 + gr) * 512 + k0 + l_col;
            gl16(&Ah[s * 512], xh + ga);
            gl16(&Bh[s * 512], Wch + gb);
            if (three) {
                gl16(&Al[s * 512], xl + ga);
                gl16(&Bl[s * 512], Wcl + gb);
            }
        }
        __syncthreads();
        if (three) {
            bf16x8 bh[4], bl[4];
            #pragma unroll
            for (int n = 0; n < 4; ++n) {
                bh[n] = ld_frag(Bh, wc * 64 + n * 16, 0, 32);
                bl[n] = ld_frag(Bl, wc * 64 + n * 16, 0, 32);
            }
            #pragma unroll
            for (int m = 0; m < 4; ++m) {
                bf16x8 ah = ld_frag(Ah, wr * 64 + m * 16, 0, 32);
                bf16x8 al = ld_frag(Al, wr * 64 + m * 16, 0, 32);
                #pragma unroll
                for (int n = 0; n < 4; ++n) {
                    acc[m][n] = MFMA16(al, bh[n], acc[m][n]);
                    acc[m][n] = MFMA16(ah, bl[n], acc[m][n]);
                    acc[m][n] = MFMA16(ah, bh[n], acc[m][n]);
                }
            }
        } else {
            bf16x8 bh[4];
            #pragma unroll
            for (int n = 0; n < 4; ++n) bh[n] = ld_frag(Bh, wc * 64 + n * 16, 0, 32);
            #pragma unroll
            for (int m = 0; m < 4; ++m) {
                bf16x8 ah = ld_frag(Ah, wr * 64 + m * 16, 0, 32);
                #pragma unroll
                for (int n = 0; n < 4; ++n) acc[m][n] = MFMA16(ah, bh[n], acc[m][n]);
            }
        }
        __syncthreads();
    }
    if (by < 4) {
        // k ssq: head = by*2+wc, per-wave 64 cols = 1 head
        const int head = by * 2 + wc;
        #pragma unroll
        for (int m = 0; m < 4; ++m)
            #pragma unroll
            for (int i = 0; i < 4; ++i) {
                float s = 0.f;
                #pragma unroll
                for (int n = 0; n < 4; ++n) { float v2 = acc[m][n][i]; s += v2 * v2; }
                s += __shfl_xor(s, 1); s += __shfl_xor(s, 2);
                s += __shfl_xor(s, 4); s += __shfl_xor(s, 8);
                if ((lane & 15) == 0) {
                    int row = row0 + wr * 64 + m * 16 + ((lane >> 4) << 2) + i;
                    int b = row >> 11, nn = row & 2047;
                    ssqbuf[(b * 8 + head) * 2048 + nn] = s;
                }
            }
    } else if (by < 8) {
        #pragma unroll
        for (int m = 0; m < 4; ++m)
            #pragma unroll
            for (int n = 0; n < 4; ++n)
                #pragma unroll
                for (int i = 0; i < 4; ++i) {
                    int row = row0 + wr * 64 + m * 16 + ((lane >> 4) << 2) + i;
                    int gc = col0 + wc * 64 + n * 16 + (lane & 15);
                    int c = gc - 512, h = c >> 6, d = c & 63;
                    int b = row >> 11, nn = row & 2047;
                    vbf[((size_t)(b * 8 + h) * 2048 + nn) * 64 + d] = f2bf(acc[m][n][i]);
                }
    } else {
        const bool isq = (by < 16);
        const int h = isq ? (by - 8) : (by - 16);
        // full-row max: per-wave 64-col max -> LDS exchange across wc
        #pragma unroll
        for (int m = 0; m < 4; ++m)
            #pragma unroll
            for (int i = 0; i < 4; ++i) {
                float mx = fmaxf(fmaxf(acc[m][0][i], acc[m][1][i]),
                                 fmaxf(acc[m][2][i], acc[m][3][i]));
                mx = fmaxf(mx, __shfl_xor(mx, 1));
                mx = fmaxf(mx, __shfl_xor(mx, 2));
                mx = fmaxf(mx, __shfl_xor(mx, 4));
                mx = fmaxf(mx, __shfl_xor(mx, 8));
                if ((lane & 15) == 0)
                    rmx[wr * 64 + m * 16 + ((lane >> 4) << 2) + i][wc] = mx;
            }
        __syncthreads();
        short* dst = isq ? phiq : pkloc;
        #pragma unroll
        for (int m = 0; m < 4; ++m)
            #pragma unroll
            for (int i = 0; i < 4; ++i) {
                int lr = wr * 64 + m * 16 + ((lane >> 4) << 2) + i;
                float fm = fmaxf(rmx[lr][0], rmx[lr][1]);
                int row = row0 + lr;
                int b = row >> 11, nn = row & 2047;
                size_t g = (size_t)(b * 8 + h) * 2048 + nn;
                #pragma unroll
                for (int n = 0; n < 4; ++n) {
                    int mc = wc * 64 + n * 16 + (lane & 15);
                    float e = expf(acc[m][n][i] - fm);
                    float val = isq ? (e * INV_SQRT_M + 1e-4f) : e;
                    dst[g * 128 + mc] = f2bf(val);
                }
                if (!isq && wc == 0 && (lane & 15) == 0) pmaxp[g] = fm;
            }
    }
}

// ---------------- global key-max: 32 blocks, 32 atomics ----------------
__global__ __launch_bounds__(256) void kmax_reduce(const float* __restrict__ pmaxp,
    const float* __restrict__ ssqbuf, unsigned* __restrict__ gmaxu)
{
    float m = -3.402823466e38f;
    for (int g = blockIdx.x * 256 + threadIdx.x; g < 32768; g += 8192)
        m = fmaxf(m, pmaxp[g] - 0.5f * ssqbuf[g]);
    #pragma unroll
    for (int off = 1; off < 64; off <<= 1) m = fmaxf(m, __shfl_xor(m, off));
    __shared__ float w[4];
    if ((threadIdx.x & 63) == 0) w[threadIdx.x >> 6] = m;
    __syncthreads();
    if (threadIdx.x == 0)
        atomicMax(gmaxu, encf(fmaxf(fmaxf(w[0], w[1]), fmaxf(w[2], w[3]))));
}

// ---------------- per-chunk KV sums: ST[d][m] = sum_n v[n][d] pk[n][m] (bf16 out) ----------------
// pk and v staged TRANSPOSED in LDS so all MFMA fragment loads are contiguous ds_read_b128
__global__ __launch_bounds__(256) void chunk_kv_mfma(
    const short* __restrict__ pkloc, const float* __restrict__ ssqbuf,
    const float* __restrict__ pmaxp, const unsigned* __restrict__ gmaxu,
    const short* __restrict__ v_bf, short* __restrict__ Sbf, float* __restrict__ ksum)
{
    __shared__ short pk_T[128][66];   // [m][n]
    __shared__ short v_T[64][66];     // [d][n]
    __shared__ float srow[64];
    const int t = threadIdx.x, lane = t & 63, wave = t >> 6;
    const int wr = wave >> 1, wc = wave & 1;
    const int bh = blockIdx.x >> 5, j = blockIdx.x & 31;
    const int n0 = j << 6;
    const float g = decf(gmaxu[0]);
    if (t < 64) {
        int gr = bh * 2048 + n0 + t;
        srow[t] = expf(pmaxp[gr] - 0.5f * ssqbuf[gr] - g) * INV_SQRT_M;
    }
    __syncthreads();
    #pragma unroll
    for (int it = 0; it < 4; ++it) {
        int idx = t + it * 256;
        int r = idx >> 4, c8 = (idx & 15) << 3;
        bf16x8 raw = *(const bf16x8*)(pkloc + ((size_t)(bh * 2048 + n0 + r)) * 128 + c8);
        float s = srow[r];
        #pragma unroll
        for (int u = 0; u < 8; ++u) pk_T[c8 + u][r] = f2bf(bf2f(raw[u]) * s + 1e-4f);
    }
    #pragma unroll
    for (int it = 0; it < 2; ++it) {
        int idx = t + it * 256;
        int r = idx >> 3, c8 = (idx & 7) << 3;
        bf16x8 raw = *(const bf16x8*)(v_bf + ((size_t)(bh * 2048 + n0 + r)) * 64 + c8);
        #pragma unroll
        for (int u = 0; u < 8; ++u) v_T[c8 + u][r] = raw[u];
    }
    __syncthreads();
    f32x4 acc[2][4];
    #pragma unroll
    for (int mi = 0; mi < 2; ++mi)
        #pragma unroll
        for (int ni = 0; ni < 4; ++ni) { f32x4 z = {0.f, 0.f, 0.f, 0.f}; acc[mi][ni] = z; }
    #pragma unroll
    for (int ks = 0; ks < 2; ++ks) {
        bf16x8 a0 = ld_frag(&v_T[0][0], wr * 32, ks * 32, 66);
        bf16x8 a1 = ld_frag(&v_T[0][0], wr * 32 + 16, ks * 32, 66);
        #pragma unroll
        for (int ni = 0; ni < 4; ++ni) {
            bf16x8 bb = ld_frag(&pk_T[0][0], wc * 64 + ni * 16, ks * 32, 66);
            acc[0][ni] = MFMA16(a0, bb, acc[0][ni]);
            acc[1][ni] = MFMA16(a1, bb, acc[1][ni]);
        }
    }
    const size_t sbase = ((size_t)blockIdx.x) << 13;
    #pragma unroll
    for (int mi = 0; mi < 2; ++mi)
        #pragma unroll
        for (int ni = 0; ni < 4; ++ni)
            #pragma unroll
            for (int i = 0; i < 4; ++i) {
                int row = wr * 32 + mi * 16 + ((lane >> 4) << 2) + i;
                int col = wc * 64 + ni * 16 + (lane & 15);
                Sbf[sbase + (size_t)row * 128 + col] = f2bf(acc[mi][ni][i]);
            }
    if (t < 128) {
        float s = 0.f;
        #pragma unroll
        for (int n8 = 0; n8 < 64; n8 += 8) {
            bf16x8 v = *(const bf16x8*)&pk_T[t][n8];
            #pragma unroll
            for (int u = 0; u < 8; ++u) s += bf2f(v[u]);
        }
        ksum[((size_t)blockIdx.x) * 128 + t] = s;
    }
}

// ---------------- exclusive prefix over chunks (vectorized bf16x8 / float4) ----------------
__global__ __launch_bounds__(256) void prefix_scan(const short* __restrict__ Sbf,
    const float* __restrict__ ksum, short* __restrict__ STbf, float* __restrict__ kpre)
{
    const int bh = blockIdx.x, y = blockIdx.y, t = threadIdx.x;
    if (y < 4) {
        int e8 = (y * 256 + t) * 8;   // within 8192-elem chunk
        size_t base = (size_t)bh * NC_ * 8192 + e8;
        float run[8] = {0.f, 0.f, 0.f, 0.f, 0.f, 0.f, 0.f, 0.f};
        #pragma unroll
        for (int j = 0; j < NC_; ++j) {
            bf16x8 v = *(const bf16x8*)(Sbf + base + (size_t)j * 8192);
            bf16x8 o;
            #pragma unroll
            for (int u = 0; u < 8; ++u) { o[u] = f2bf(run[u]); run[u] += bf2f(v[u]); }
            *(bf16x8*)(STbf + base + (size_t)j * 8192) = o;
        }
    } else if (t < 32) {
        size_t base = (size_t)bh * NC_ * 128 + t * 4;
        float r0 = 0.f, r1 = 0.f, r2 = 0.f, r3 = 0.f;
        #pragma unroll
        for (int j = 0; j < NC_; ++j) {
            float4 v = *(const float4*)(ksum + base + (size_t)j * 128);
            float4 o; o.x = r0; o.y = r1; o.z = r2; o.w = r3;
            *(float4*)(kpre + base + (size_t)j * 128) = o;
            r0 += v.x; r1 += v.y; r2 += v.z; r3 += v.w;
        }
    }
}

// ---------------- per-chunk output (MFMA); o written bf16 (no lo split) ----------------
__global__ __launch_bounds__(256) void chunk_out_mfma(
    const short* __restrict__ phi_q, const short* __restrict__ pkloc,
    const float* __restrict__ ssqbuf, const float* __restrict__ pmaxp,
    const unsigned* __restrict__ gmaxu,
    const short* __restrict__ v_bf, const short* __restrict__ STbf,
    const float* __restrict__ kpre, short* __restrict__ o_bf)
{
    __shared__ short pq_l[64][136];
    __shared__ short pkst_l[64][136];
    __shared__ short v_T[64][66];     // [d][n]
    __shared__ short a_l[64][72];
    __shared__ float rsum[64][8];
    __shared__ float den[64];
    __shared__ float ksp_l[128];
    __shared__ float srow[64];
    const int t = threadIdx.x, lane = t & 63, wave = t >> 6;
    const int wr = wave >> 1, wc = wave & 1;
    const int bh = blockIdx.x >> 5, j = blockIdx.x & 31;
    const int n0 = j << 6;
    const size_t prow = (size_t)bh * N_ + n0;
    const float g = decf(gmaxu[0]);
    if (t < 64) {
        int gr = bh * 2048 + n0 + t;
        srow[t] = expf(pmaxp[gr] - 0.5f * ssqbuf[gr] - g) * INV_SQRT_M;
    }
    if (t < 128) ksp_l[t] = kpre[((size_t)bh * NC_ + j) * 128 + t];
    __syncthreads();
    #pragma unroll
    for (int it = 0; it < 4; ++it) {
        int idx = t + it * 256;
        int r = idx >> 4, c8 = (idx & 15) << 3;
        *(bf16x8*)&pq_l[r][c8] = *(const bf16x8*)(phi_q + (prow + r) * 128 + c8);
        bf16x8 raw = *(const bf16x8*)(pkloc + (prow + r) * 128 + c8);
        float s = srow[r];
        bf16x8 o;
        #pragma unroll
        for (int u = 0; u < 8; ++u) o[u] = f2bf(bf2f(raw[u]) * s + 1e-4f);
        *(bf16x8*)&pkst_l[r][c8] = o;
    }
    #pragma unroll
    for (int it = 0; it < 2; ++it) {
        int idx = t + it * 256;
        int r = idx >> 3, c8 = (idx & 7) << 3;
        bf16x8 raw = *(const bf16x8*)(v_bf + (prow + r) * 64 + c8);
        #pragma unroll
        for (int u = 0; u < 8; ++u) v_T[c8 + u][r] = raw[u];
    }
    __syncthreads();
    f32x4 qk[2][2];
    #pragma unroll
    for (int mi = 0; mi < 2; ++mi)
        #pragma unroll
        for (int ni = 0; ni < 2; ++ni) { f32x4 z = {0.f, 0.f, 0.f, 0.f}; qk[mi][ni] = z; }
    #pragma unroll
    for (int ks = 0; ks < 4; ++ks) {
        bf16x8 a0 = ld_frag(&pq_l[0][0], wr * 32, ks * 32, 136);
        bf16x8 a1 = ld_frag(&pq_l[0][0], wr * 32 + 16, ks * 32, 136);
        bf16x8 b0 = ld_frag(&pkst_l[0][0], wc * 32, ks * 32, 136);
        bf16x8 b1 = ld_frag(&pkst_l[0][0], wc * 32 + 16, ks * 32, 136);
        qk[0][0] = MFMA16(a0, b0, qk[0][0]);
        qk[0][1] = MFMA16(a0, b1, qk[0][1]);
        qk[1][0] = MFMA16(a1, b0, qk[1][0]);
        qk[1][1] = MFMA16(a1, b1, qk[1][1]);
    }
    #pragma unroll
    for (int mi = 0; mi < 2; ++mi)
        #pragma unroll
        for (int i = 0; i < 4; ++i) {
            int row = wr * 32 + mi * 16 + ((lane >> 4) << 2) + i;
            float part = 0.f;
            #pragma unroll
            for (int ni = 0; ni < 2; ++ni) {
                int col = wc * 32 + ni * 16 + (lane & 15);
                float val = (col <= row) ? qk[mi][ni][i] : 0.f;
                a_l[row][col] = f2bf(val);
                part += val;
            }
            part += __shfl_xor(part, 1);
            part += __shfl_xor(part, 2);
            part += __shfl_xor(part, 4);
            part += __shfl_xor(part, 8);
            if ((lane & 15) == 0) rsum[row][wc] = part;
        }
    {
        int row = t & 63, qq = t >> 6;
        float s = 0.f;
        #pragma unroll
        for (int m = 0; m < 32; ++m) s += bf2f(pq_l[row][qq * 32 + m]) * ksp_l[qq * 32 + m];
        rsum[row][4 + qq] = s;
    }
    __syncthreads();
    #pragma unroll
    for (int it = 0; it < 4; ++it) {
        int idx = t + it * 256;
        int r = idx >> 4, c8 = (idx & 15) << 3;
        *(bf16x8*)&pkst_l[r][c8] =
            *(const bf16x8*)(STbf + (((size_t)bh * NC_ + j) << 13) + r * 128 + c8);
    }
    if (t < 64) {
        float s = rsum[t][0] + rsum[t][1] + rsum[t][4] + rsum[t][5] + rsum[t][6] + rsum[t][7];
        den[t] = 1.0f / (s + 1e-6f);
    }
    __syncthreads();
    f32x4 oa[2][2];
    #pragma unroll
    for (int mi = 0; mi < 2; ++mi)
        #pragma unroll
        for (int ni = 0; ni < 2; ++ni) { f32x4 z = {0.f, 0.f, 0.f, 0.f}; oa[mi][ni] = z; }
    #pragma unroll
    for (int ks = 0; ks < 2; ++ks) {
        bf16x8 a0 = ld_frag(&a_l[0][0], wr * 32, ks * 32, 72);
        bf16x8 a1 = ld_frag(&a_l[0][0], wr * 32 + 16, ks * 32, 72);
        #pragma unroll
        for (int ni = 0; ni < 2; ++ni) {
            bf16x8 bb = ld_frag(&v_T[0][0], wc * 32 + ni * 16, ks * 32, 66);
            oa[0][ni] = MFMA16(a0, bb, oa[0][ni]);
            oa[1][ni] = MFMA16(a1, bb, oa[1][ni]);
        }
    }
    #pragma unroll
    for (int ks = 0; ks < 4; ++ks) {
        bf16x8 a0 = ld_frag(&pq_l[0][0], wr * 32, ks * 32, 136);
        bf16x8 a1 = ld_frag(&pq_l[0][0], wr * 32 + 16, ks * 32, 136);
        #pragma unroll
        for (int ni = 0; ni < 2; ++ni) {
            bf16x8 bb = ld_frag(&pkst_l[0][0], wc * 32 + ni * 16, ks * 32, 136);
            oa[0][ni] = MFMA16(a0, bb, oa[0][ni]);
            oa[1][ni] = MFMA16(a1, bb, oa[1][ni]);
        }
    }
    const int b_ = bh >> 3, h = bh & 7;
    #pragma unroll
    for (int mi = 0; mi < 2; ++mi)
        #pragma unroll
        for (int ni = 0; ni < 2; ++ni)
            #pragma unroll
            for (int i = 0; i < 4; ++i) {
                int row = wr * 32 + mi * 16 + ((lane >> 4) << 2) + i;
                int col = wc * 32 + ni * 16 + (lane & 15);
                float val = oa[mi][ni][i] * den[row];
                size_t oi = ((size_t)b_ * N_ + n0 + row) * 512 + h * 64 + col;
                o_bf[oi] = f2bf(val);
            }
}

// ---------------- output projection: out = o @ Woh^T + bo; 128x64 tiles ----------------
__global__ __launch_bounds__(256) void gemm_out(
    const short* __restrict__ o_bf, const short* __restrict__ Woh,
    const float* __restrict__ bo, float* __restrict__ out)
{
    __shared__ short Ah[128 * 32];
    __shared__ short Bh[64 * 32];
    const int t = threadIdx.x, lane = t & 63, wave = t >> 6;
    const int row0 = blockIdx.x * 128, col0 = blockIdx.y * 64;
    const int l_row = lane >> 2, l_col = (lane & 3) << 3;
    f32x4 acc[2][4];
    #pragma unroll
    for (int m = 0; m < 2; ++m)
        #pragma unroll
        for (int n = 0; n < 4; ++n) { f32x4 z = {0.f, 0.f, 0.f, 0.f}; acc[m][n] = z; }
    for (int k0 = 0; k0 < 512; k0 += 32) {
        #pragma unroll
        for (int sub = 0; sub < 2; ++sub) {
            int s = wave * 2 + sub;
            int gr = s * 16 + l_row;
            size_t ga = (size_t)(row0 + gr) * 512 + k0 + l_col;
            gl16(&Ah[s * 512], o_bf + ga);
        }
        {
            int gr = wave * 16 + l_row;
            size_t gb = (size_t)(col0 + gr) * 512 + k0 + l_col;
            gl16(&Bh[wave * 512], Woh + gb);
        }
        __syncthreads();
        bf16x8 bh[4];
        #pragma unroll
        for (int n = 0; n < 4; ++n) bh[n] = ld_frag(Bh, n * 16, 0, 32);
        #pragma unroll
        for (int m = 0; m < 2; ++m) {
            bf16x8 ah = ld_frag(Ah, wave * 32 + m * 16, 0, 32);
            #pragma unroll
            for (int n = 0; n < 4; ++n)
                acc[m][n] = MFMA16(ah, bh[n], acc[m][n]);
        }
        __syncthreads();
    }
    #pragma unroll
    for (int m = 0; m < 2; ++m)
        #pragma unroll
        for (int n = 0; n < 4; ++n)
            #pragma unroll
            for (int i = 0; i < 4; ++i) {
                int gr = row0 + wave * 32 + m * 16 + ((lane >> 4) << 2) + i;
                int gc = col0 + n * 16 + (lane & 15);
                out[(size_t)gr * 512 + gc] = acc[m][n][i] + bo[gc];
            }
}

extern "C" void kernel_launch(void* const* d_in, const int* in_sizes, int n_in,
                              void* d_out, int out_size, void* d_ws, size_t ws_size,
                              hipStream_t stream) {
    const float* x     = (const float*)d_in[0];
    const float* omega = (const float*)d_in[1];
    const float* Wq    = (const float*)d_in[2];
    const float* Wk    = (const float*)d_in[3];
    const float* Wv    = (const float*)d_in[4];
    const float* Wo    = (const float*)d_in[5];
    const float* bo    = (const float*)d_in[6];
    float* out = (float*)d_out;

    char* w = (char*)d_ws;
    short* xh   = (short*)(w);                                  // 0..4 MB
    short* xl   = (short*)(w + (4ull  << 20));                  // 4..8
    short* Wch  = (short*)(w + (8ull  << 20));                  // 8..11 (3072x512 bf16)
    short* Wcl  = (short*)(w + (11ull << 20));                  // 11..14
    short* Woh  = (short*)(w + (14ull << 20));                  // 14..14.5
    short* phiq = (short*)(w + (15ull << 20));                  // 15..23
    short* pkloc= (short*)(w + (23ull << 20));                  // 23..31
    short* vbf  = (short*)(w + (31ull << 20));                  // 31..35
    short* Sbf  = (short*)(w + (35ull << 20));                  // 35..43
    short* STbf = (short*)(w + (43ull << 20));                  // 43..51
    short* obf  = (short*)(w + (51ull << 20));                  // 51..55
    float* ssqb = (float*)(w + (59ull << 20));                            // 128 KB
    float* pmaxp= (float*)(w + (59ull << 20) + (128ull << 10));           // 128 KB
    float* ksum = (float*)(w + (59ull << 20) + (256ull << 10));           // 256 KB
    float* kpre = (float*)(w + (59ull << 20) + (512ull << 10));           // 256 KB
    unsigned* gmaxu = (unsigned*)(w + (59ull << 20) + (768ull << 10));    // 4 B

    prep_all<<<2944, 256, 0, stream>>>(x, Wq, Wk, Wv, Wo, omega,
                                       xh, xl, Wch, Wcl, Woh, gmaxu);
    gemm_fused<<<dim3(32, 24), 256, 0, stream>>>(xh, xl, Wch, Wcl, phiq, pkloc,
                                                 vbf, ssqb, pmaxp);
    kmax_reduce<<<32, 256, 0, stream>>>(pmaxp, ssqb, gmaxu);
    chunk_kv_mfma<<<512, 256, 0, stream>>>(pkloc, ssqb, pmaxp, gmaxu, vbf, Sbf, ksum);
    prefix_scan<<<dim3(16, 5), 256, 0, stream>>>(Sbf, ksum, STbf, kpre);
    chunk_out_mfma<<<512, 256, 0, stream>>>(phiq, pkloc, ssqb, pmaxp, gmaxu,
                                            vbf, STbf, kpre, obf);
    gemm_out<<<dim3(32, 8), 256, 0, stream>>>(obf, Woh, bo, out);
}

// Round 10
// 170.384 us; speedup vs baseline: 1.0419x; 1.0419x over previous
//
#include <hip/hip_runtime.h>
#include <math.h>

#define B_ 2
#define N_ 2048
#define DIM_ 512
#define H_ 8
#define D_ 64
#define M_ 128
#define NC_ 32
#define C_ 64

#define INV_SQRT_M 0.08838834764831845f
#define QK_SCALE 0.35355339059327373f

typedef __attribute__((ext_vector_type(8))) short bf16x8;
typedef __attribute__((ext_vector_type(4))) short bf16x4;
typedef __attribute__((ext_vector_type(4))) float f32x4;

#define MFMA16(a, b, c) __builtin_amdgcn_mfma_f32_16x16x32_bf16((a), (b), (c), 0, 0, 0)

__device__ __forceinline__ short f2bf(float f) {
    union { float f; unsigned u; } x; x.f = f;
    unsigned r = (x.u + 0x7FFFu + ((x.u >> 16) & 1u)) >> 16;
    return (short)r;
}
__device__ __forceinline__ float bf2f(short s) {
    union { unsigned u; float f; } x; x.u = ((unsigned)(unsigned short)s) << 16;
    return x.f;
}
// monotone float<->uint encoding for atomicMax on floats (incl. negatives)
__device__ __forceinline__ unsigned encf(float f) {
    unsigned u = __float_as_uint(f);
    return (u & 0x80000000u) ? ~u : (u | 0x80000000u);
}
__device__ __forceinline__ float decf(unsigned e) {
    unsigned u = (e & 0x80000000u) ? (e & 0x7FFFFFFFu) : ~e;
    return __uint_as_float(u);
}

// async global->LDS 16B copy: LDS dst = (wave-uniform base) + lane*16
__device__ __forceinline__ void gl16(void* lds, const void* g) {
    __builtin_amdgcn_global_load_lds(
        (const __attribute__((address_space(1))) unsigned int*)g,
        (__attribute__((address_space(3))) unsigned int*)lds,
        16, 0, 0);
}

// fragment load from row-major LDS tile [rows][ldk] bf16 (A or B^T form)
__device__ __forceinline__ bf16x8 ld_frag(const short* base, int row0, int k0, int ldk) {
    const int lane = threadIdx.x & 63;
    return *(const bf16x8*)(base + (row0 + (lane & 15)) * ldk + k0 + ((lane >> 4) << 3));
}

// ---------------- prep (merged): x->bf16 hi; hi-only Wk/Wv/Wo; omega@W rows hi/lo; gmax init ----------------
__global__ __launch_bounds__(256) void prep_all(
    const float* __restrict__ x, const float* __restrict__ Wq, const float* __restrict__ Wk,
    const float* __restrict__ Wv, const float* __restrict__ Wo, const float* __restrict__ omega,
    short* __restrict__ xh,
    short* __restrict__ Wch, short* __restrict__ Wcl,
    short* __restrict__ Woh, unsigned* __restrict__ gmaxu)
{
    __shared__ float Ws[64][65];
    __shared__ float om[128][64];
    const int t = threadIdx.x;
    const int bid = blockIdx.x;
    if (bid < 2816) {
        int i4 = bid * 256 + t;
        if (i4 == 0) gmaxu[0] = 0u;   // < enc of any real float
        if (i4 < 524288) {
            float4 v = *(const float4*)(x + (size_t)i4 * 4);
            bf16x4 hi;
            hi[0] = f2bf(v.x); hi[1] = f2bf(v.y);
            hi[2] = f2bf(v.z); hi[3] = f2bf(v.w);
            *(bf16x4*)(xh + (size_t)i4 * 4) = hi;
        } else {
            int r = i4 - 524288;
            int widx = r >> 16, off4 = r & 65535;
            const float* src; short* dst; float sc;
            if (widx == 0)      { src = Wk; dst = Wch;          sc = QK_SCALE; }
            else if (widx == 1) { src = Wv; dst = Wch + 262144; sc = 1.f; }
            else                { src = Wo; dst = Woh;          sc = 1.f; }
            float4 v = *(const float4*)(src + (size_t)off4 * 4);
            bf16x4 hi;
            hi[0] = f2bf(v.x * sc); hi[1] = f2bf(v.y * sc);
            hi[2] = f2bf(v.z * sc); hi[3] = f2bf(v.w * sc);
            *(bf16x4*)(dst + (size_t)off4 * 4) = hi;
        }
    } else {
        // omega @ (W*scale) -> Wcomb rows 1024..3072, hi/lo
        const int bx = bid - 2816;
        const int qk = bx >> 6, h = (bx >> 3) & 7, cb = bx & 7;
        const int col0 = cb * 64;
        const float* W = qk ? Wk : Wq;
        for (int i = t; i < 64 * 64; i += 256) {
            int d = i >> 6, c = i & 63;
            Ws[d][c] = W[(size_t)(h * 64 + d) * 512 + col0 + c] * QK_SCALE;
        }
        for (int i = t; i < 128 * 64; i += 256) om[i >> 6][i & 63] = omega[i];
        __syncthreads();
        const int lane = t & 63, w = t >> 6;
        const int c = col0 + lane;
        float Wcol[64];
        #pragma unroll
        for (int d = 0; d < 64; ++d) Wcol[d] = Ws[d][lane];
        for (int mi = 0; mi < 32; ++mi) {
            int m = w * 32 + mi;
            float acc = 0.f;
            #pragma unroll
            for (int d = 0; d < 64; d += 4) {
                float4 o4 = *(const float4*)&om[m][d];
                acc += o4.x * Wcol[d] + o4.y * Wcol[d+1] + o4.z * Wcol[d+2] + o4.w * Wcol[d+3];
            }
            int row = 1024 + qk * 1024 + h * 128 + m;
            short hi = f2bf(acc);
            Wch[(size_t)row * 512 + c] = hi;
            Wcl[(size_t)row * 512 + c] = f2bf(acc - bf2f(hi));
        }
    }
}

// ---------------- fused GEMM: [4096 x 3072] = x @ Wcomb^T ----------------
// cols [0,512) k->ssq (1-pass); [512,1024) v->bf16 (1-pass);
//      [1024,2048) projq -> phiq bf16 (2-pass hi/lo-B, in-epilogue row-max + exp);
//      [2048,3072) projk -> pk_local bf16 + pmaxp (2-pass)
__global__ __launch_bounds__(256) void gemm_fused(
    const short* __restrict__ xh,
    const short* __restrict__ Wch, const short* __restrict__ Wcl,
    short* __restrict__ phiq, short* __restrict__ pkloc,
    short* __restrict__ vbf, float* __restrict__ ssqbuf, float* __restrict__ pmaxp)
{
    __shared__ short Ah[128 * 32];
    __shared__ short Bh[128 * 32];
    __shared__ short Bl[128 * 32];
    __shared__ float rmx[128][2];
    const int t = threadIdx.x, lane = t & 63, wave = t >> 6;
    const int wr = wave >> 1, wc = wave & 1;
    const int row0 = blockIdx.x * 128;
    const int by = blockIdx.y;
    const int col0 = by * 128;
    const int l_row = lane >> 2, l_col = (lane & 3) << 3;
    const bool two = (by >= 8);
    f32x4 acc[4][4];
    #pragma unroll
    for (int m = 0; m < 4; ++m)
        #pragma unroll
        for (int n = 0; n < 4; ++n) { f32x4 z = {0.f, 0.f, 0.f, 0.f}; acc[m][n] = z; }
    for (int k0 = 0; k0 < 512; k0 += 32) {
        #pragma unroll
        for (int sub = 0; sub < 2; ++sub) {
            int s = wave * 2 + sub;
            int gr = s * 16 + l_row;
            size_t ga = (size_t)(row0 + gr) * 512 + k0 + l_col;
            size_t gb = (size_t)(col0 + gr) * 512 + k0 + l_col;
            gl16(&Ah[s * 512], xh + ga);
            gl16(&Bh[s * 512], Wch + gb);
            if (two) gl16(&Bl[s * 512], Wcl + gb);
        }
        __syncthreads();
        if (two) {
            bf16x8 bh[4], bl[4];
            #pragma unroll
            for (int n = 0; n < 4; ++n) {
                bh[n] = ld_frag(Bh, wc * 64 + n * 16, 0, 32);
                bl[n] = ld_frag(Bl, wc * 64 + n * 16, 0, 32);
            }
            #pragma unroll
            for (int m = 0; m < 4; ++m) {
                bf16x8 ah = ld_frag(Ah, wr * 64 + m * 16, 0, 32);
                #pragma unroll
                for (int n = 0; n < 4; ++n) {
                    acc[m][n] = MFMA16(ah, bl[n], acc[m][n]);
                    acc[m][n] = MFMA16(ah, bh[n], acc[m][n]);
                }
            }
        } else {
            bf16x8 bh[4];
            #pragma unroll
            for (int n = 0; n < 4; ++n) bh[n] = ld_frag(Bh, wc * 64 + n * 16, 0, 32);
            #pragma unroll
            for (int m = 0; m < 4; ++m) {
                bf16x8 ah = ld_frag(Ah, wr * 64 + m * 16, 0, 32);
                #pragma unroll
                for (int n = 0; n < 4; ++n) acc[m][n] = MFMA16(ah, bh[n], acc[m][n]);
            }
        }
        __syncthreads();
    }
    if (by < 4) {
        // k ssq: head = by*2+wc, per-wave 64 cols = 1 head
        const int head = by * 2 + wc;
        #pragma unroll
        for (int m = 0; m < 4; ++m)
            #pragma unroll
            for (int i = 0; i < 4; ++i) {
                float s = 0.f;
                #pragma unroll
                for (int n = 0; n < 4; ++n) { float v2 = acc[m][n][i]; s += v2 * v2; }
                s += __shfl_xor(s, 1); s += __shfl_xor(s, 2);
                s += __shfl_xor(s, 4); s += __shfl_xor(s, 8);
                if ((lane & 15) == 0) {
                    int row = row0 + wr * 64 + m * 16 + ((lane >> 4) << 2) + i;
                    int b = row >> 11, nn = row & 2047;
                    ssqbuf[(b * 8 + head) * 2048 + nn] = s;
                }
            }
    } else if (by < 8) {
        #pragma unroll
        for (int m = 0; m < 4; ++m)
            #pragma unroll
            for (int n = 0; n < 4; ++n)
                #pragma unroll
                for (int i = 0; i < 4; ++i) {
                    int row = row0 + wr * 64 + m * 16 + ((lane >> 4) << 2) + i;
                    int gc = col0 + wc * 64 + n * 16 + (lane & 15);
                    int c = gc - 512, h = c >> 6, d = c & 63;
                    int b = row >> 11, nn = row & 2047;
                    vbf[((size_t)(b * 8 + h) * 2048 + nn) * 64 + d] = f2bf(acc[m][n][i]);
                }
    } else {
        const bool isq = (by < 16);
        const int h = isq ? (by - 8) : (by - 16);
        // full-row max: per-wave 64-col max -> LDS exchange across wc
        #pragma unroll
        for (int m = 0; m < 4; ++m)
            #pragma unroll
            for (int i = 0; i < 4; ++i) {
                float mx = fmaxf(fmaxf(acc[m][0][i], acc[m][1][i]),
                                 fmaxf(acc[m][2][i], acc[m][3][i]));
                mx = fmaxf(mx, __shfl_xor(mx, 1));
                mx = fmaxf(mx, __shfl_xor(mx, 2));
                mx = fmaxf(mx, __shfl_xor(mx, 4));
                mx = fmaxf(mx, __shfl_xor(mx, 8));
                if ((lane & 15) == 0)
                    rmx[wr * 64 + m * 16 + ((lane >> 4) << 2) + i][wc] = mx;
            }
        __syncthreads();
        short* dst = isq ? phiq : pkloc;
        #pragma unroll
        for (int m = 0; m < 4; ++m)
            #pragma unroll
            for (int i = 0; i < 4; ++i) {
                int lr = wr * 64 + m * 16 + ((lane >> 4) << 2) + i;
                float fm = fmaxf(rmx[lr][0], rmx[lr][1]);
                int row = row0 + lr;
                int b = row >> 11, nn = row & 2047;
                size_t g = (size_t)(b * 8 + h) * 2048 + nn;
                #pragma unroll
                for (int n = 0; n < 4; ++n) {
                    int mc = wc * 64 + n * 16 + (lane & 15);
                    float e = expf(acc[m][n][i] - fm);
                    float val = isq ? (e * INV_SQRT_M + 1e-4f) : e;
                    dst[g * 128 + mc] = f2bf(val);
                }
                if (!isq && wc == 0 && (lane & 15) == 0) pmaxp[g] = fm;
            }
    }
}

// ---------------- global key-max: 32 blocks, 32 atomics ----------------
__global__ __launch_bounds__(256) void kmax_reduce(const float* __restrict__ pmaxp,
    const float* __restrict__ ssqbuf, unsigned* __restrict__ gmaxu)
{
    float m = -3.402823466e38f;
    for (int g = blockIdx.x * 256 + threadIdx.x; g < 32768; g += 8192)
        m = fmaxf(m, pmaxp[g] - 0.5f * ssqbuf[g]);
    #pragma unroll
    for (int off = 1; off < 64; off <<= 1) m = fmaxf(m, __shfl_xor(m, off));
    __shared__ float w[4];
    if ((threadIdx.x & 63) == 0) w[threadIdx.x >> 6] = m;
    __syncthreads();
    if (threadIdx.x == 0)
        atomicMax(gmaxu, encf(fmaxf(fmaxf(w[0], w[1]), fmaxf(w[2], w[3]))));
}

// ---------------- per-chunk KV sums: ST[d][m] = sum_n v[n][d] pk[n][m] (bf16 out) ----------------
// pk and v staged TRANSPOSED in LDS so all MFMA fragment loads are contiguous ds_read_b128
__global__ __launch_bounds__(256) void chunk_kv_mfma(
    const short* __restrict__ pkloc, const float* __restrict__ ssqbuf,
    const float* __restrict__ pmaxp, const unsigned* __restrict__ gmaxu,
    const short* __restrict__ v_bf, short* __restrict__ Sbf, float* __restrict__ ksum)
{
    __shared__ short pk_T[128][66];   // [m][n]
    __shared__ short v_T[64][66];     // [d][n]
    __shared__ float srow[64];
    const int t = threadIdx.x, lane = t & 63, wave = t >> 6;
    const int wr = wave >> 1, wc = wave & 1;
    const int bh = blockIdx.x >> 5, j = blockIdx.x & 31;
    const int n0 = j << 6;
    const float g = decf(gmaxu[0]);
    if (t < 64) {
        int gr = bh * 2048 + n0 + t;
        srow[t] = expf(pmaxp[gr] - 0.5f * ssqbuf[gr] - g) * INV_SQRT_M;
    }
    __syncthreads();
    #pragma unroll
    for (int it = 0; it < 4; ++it) {
        int idx = t + it * 256;
        int r = idx >> 4, c8 = (idx & 15) << 3;
        bf16x8 raw = *(const bf16x8*)(pkloc + ((size_t)(bh * 2048 + n0 + r)) * 128 + c8);
        float s = srow[r];
        #pragma unroll
        for (int u = 0; u < 8; ++u) pk_T[c8 + u][r] = f2bf(bf2f(raw[u]) * s + 1e-4f);
    }
    #pragma unroll
    for (int it = 0; it < 2; ++it) {
        int idx = t + it * 256;
        int r = idx >> 3, c8 = (idx & 7) << 3;
        bf16x8 raw = *(const bf16x8*)(v_bf + ((size_t)(bh * 2048 + n0 + r)) * 64 + c8);
        #pragma unroll
        for (int u = 0; u < 8; ++u) v_T[c8 + u][r] = raw[u];
    }
    __syncthreads();
    f32x4 acc[2][4];
    #pragma unroll
    for (int mi = 0; mi < 2; ++mi)
        #pragma unroll
        for (int ni = 0; ni < 4; ++ni) { f32x4 z = {0.f, 0.f, 0.f, 0.f}; acc[mi][ni] = z; }
    #pragma unroll
    for (int ks = 0; ks < 2; ++ks) {
        bf16x8 a0 = ld_frag(&v_T[0][0], wr * 32, ks * 32, 66);
        bf16x8 a1 = ld_frag(&v_T[0][0], wr * 32 + 16, ks * 32, 66);
        #pragma unroll
        for (int ni = 0; ni < 4; ++ni) {
            bf16x8 bb = ld_frag(&pk_T[0][0], wc * 64 + ni * 16, ks * 32, 66);
            acc[0][ni] = MFMA16(a0, bb, acc[0][ni]);
            acc[1][ni] = MFMA16(a1, bb, acc[1][ni]);
        }
    }
    const size_t sbase = ((size_t)blockIdx.x) << 13;
    #pragma unroll
    for (int mi = 0; mi < 2; ++mi)
        #pragma unroll
        for (int ni = 0; ni < 4; ++ni)
            #pragma unroll
            for (int i = 0; i < 4; ++i) {
                int row = wr * 32 + mi * 16 + ((lane >> 4) << 2) + i;
                int col = wc * 64 + ni * 16 + (lane & 15);
                Sbf[sbase + (size_t)row * 128 + col] = f2bf(acc[mi][ni][i]);
            }
    if (t < 128) {
        float s = 0.f;
        #pragma unroll
        for (int n8 = 0; n8 < 64; n8 += 8) {
            bf16x8 v = *(const bf16x8*)&pk_T[t][n8];
            #pragma unroll
            for (int u = 0; u < 8; ++u) s += bf2f(v[u]);
        }
        ksum[((size_t)blockIdx.x) * 128 + t] = s;
    }
}

// ---------------- exclusive prefix over chunks (vectorized bf16x8 / float4) ----------------
__global__ __launch_bounds__(256) void prefix_scan(const short* __restrict__ Sbf,
    const float* __restrict__ ksum, short* __restrict__ STbf, float* __restrict__ kpre)
{
    const int bh = blockIdx.x, y = blockIdx.y, t = threadIdx.x;
    if (y < 4) {
        int e8 = (y * 256 + t) * 8;   // within 8192-elem chunk
        size_t base = (size_t)bh * NC_ * 8192 + e8;
        float run[8] = {0.f, 0.f, 0.f, 0.f, 0.f, 0.f, 0.f, 0.f};
        #pragma unroll
        for (int j = 0; j < NC_; ++j) {
            bf16x8 v = *(const bf16x8*)(Sbf + base + (size_t)j * 8192);
            bf16x8 o;
            #pragma unroll
            for (int u = 0; u < 8; ++u) { o[u] = f2bf(run[u]); run[u] += bf2f(v[u]); }
            *(bf16x8*)(STbf + base + (size_t)j * 8192) = o;
        }
    } else if (t < 32) {
        size_t base = (size_t)bh * NC_ * 128 + t * 4;
        float r0 = 0.f, r1 = 0.f, r2 = 0.f, r3 = 0.f;
        #pragma unroll
        for (int j = 0; j < NC_; ++j) {
            float4 v = *(const float4*)(ksum + base + (size_t)j * 128);
            float4 o; o.x = r0; o.y = r1; o.z = r2; o.w = r3;
            *(float4*)(kpre + base + (size_t)j * 128) = o;
            r0 += v.x; r1 += v.y; r2 += v.z; r3 += v.w;
        }
    }
}

// ---------------- per-chunk output (MFMA); o written bf16 (no lo split) ----------------
__global__ __launch_bounds__(256) void chunk_out_mfma(
    const short* __restrict__ phi_q, const short* __restrict__ pkloc,
    const float* __restrict__ ssqbuf, const float* __restrict__ pmaxp,
    const unsigned* __restrict__ gmaxu,
    const short* __restrict__ v_bf, const short* __restrict__ STbf,
    const float* __restrict__ kpre, short* __restrict__ o_bf)
{
    __shared__ short pq_l[64][136];
    __shared__ short pkst_l[64][136];
    __shared__ short v_T[64][66];     // [d][n]
    __shared__ short a_l[64][72];
    __shared__ float rsum[64][8];
    __shared__ float den[64];
    __shared__ float ksp_l[128];
    __shared__ float srow[64];
    const int t = threadIdx.x, lane = t & 63, wave = t >> 6;
    const int wr = wave >> 1, wc = wave & 1;
    const int bh = blockIdx.x >> 5, j = blockIdx.x & 31;
    const int n0 = j << 6;
    const size_t prow = (size_t)bh * N_ + n0;
    const float g = decf(gmaxu[0]);
    if (t < 64) {
        int gr = bh * 2048 + n0 + t;
        srow[t] = expf(pmaxp[gr] - 0.5f * ssqbuf[gr] - g) * INV_SQRT_M;
    }
    if (t < 128) ksp_l[t] = kpre[((size_t)bh * NC_ + j) * 128 + t];
    __syncthreads();
    #pragma unroll
    for (int it = 0; it < 4; ++it) {
        int idx = t + it * 256;
        int r = idx >> 4, c8 = (idx & 15) << 3;
        *(bf16x8*)&pq_l[r][c8] = *(const bf16x8*)(phi_q + (prow + r) * 128 + c8);
        bf16x8 raw = *(const bf16x8*)(pkloc + (prow + r) * 128 + c8);
        float s = srow[r];
        bf16x8 o;
        #pragma unroll
        for (int u = 0; u < 8; ++u) o[u] = f2bf(bf2f(raw[u]) * s + 1e-4f);
        *(bf16x8*)&pkst_l[r][c8] = o;
    }
    #pragma unroll
    for (int it = 0; it < 2; ++it) {
        int idx = t + it * 256;
        int r = idx >> 3, c8 = (idx & 7) << 3;
        bf16x8 raw = *(const bf16x8*)(v_bf + (prow + r) * 64 + c8);
        #pragma unroll
        for (int u = 0; u < 8; ++u) v_T[c8 + u][r] = raw[u];
    }
    __syncthreads();
    f32x4 qk[2][2];
    #pragma unroll
    for (int mi = 0; mi < 2; ++mi)
        #pragma unroll
        for (int ni = 0; ni < 2; ++ni) { f32x4 z = {0.f, 0.f, 0.f, 0.f}; qk[mi][ni] = z; }
    #pragma unroll
    for (int ks = 0; ks < 4; ++ks) {
        bf16x8 a0 = ld_frag(&pq_l[0][0], wr * 32, ks * 32, 136);
        bf16x8 a1 = ld_frag(&pq_l[0][0], wr * 32 + 16, ks * 32, 136);
        bf16x8 b0 = ld_frag(&pkst_l[0][0], wc * 32, ks * 32, 136);
        bf16x8 b1 = ld_frag(&pkst_l[0][0], wc * 32 + 16, ks * 32, 136);
        qk[0][0] = MFMA16(a0, b0, qk[0][0]);
        qk[0][1] = MFMA16(a0, b1, qk[0][1]);
        qk[1][0] = MFMA16(a1, b0, qk[1][0]);
        qk[1][1] = MFMA16(a1, b1, qk[1][1]);
    }
    #pragma unroll
    for (int mi = 0; mi < 2; ++mi)
        #pragma unroll
        for (int i = 0; i < 4; ++i) {
            int row = wr * 32 + mi * 16 + ((lane >> 4) << 2) + i;
            float part = 0.f;
            #pragma unroll
            for (int ni = 0; ni < 2; ++ni) {
                int col = wc * 32 + ni * 16 + (lane & 15);
                float val = (col <= row) ? qk[mi][ni][i] : 0.f;
                a_l[row][col] = f2bf(val);
                part += val;
            }
            part += __shfl_xor(part, 1);
            part += __shfl_xor(part, 2);
            part += __shfl_xor(part, 4);
            part += __shfl_xor(part, 8);
            if ((lane & 15) == 0) rsum[row][wc] = part;
        }
    {
        int row = t & 63, qq = t >> 6;
        float s = 0.f;
        #pragma unroll
        for (int m = 0; m < 32; ++m) s += bf2f(pq_l[row][qq * 32 + m]) * ksp_l[qq * 32 + m];
        rsum[row][4 + qq] = s;
    }
    __syncthreads();
    #pragma unroll
    for (int it = 0; it < 4; ++it) {
        int idx = t + it * 256;
        int r = idx >> 4, c8 = (idx & 15) << 3;
        *(bf16x8*)&pkst_l[r][c8] =
            *(const bf16x8*)(STbf + (((size_t)bh * NC_ + j) << 13) + r * 128 + c8);
    }
    if (t < 64) {
        float s = rsum[t][0] + rsum[t][1] + rsum[t][4] + rsum[t][5] + rsum[t][6] + rsum[t][7];
        den[t] = 1.0f / (s + 1e-6f);
    }
    __syncthreads();
    f32x4 oa[2][2];
    #pragma unroll
    for (int mi = 0; mi < 2; ++mi)
        #pragma unroll
        for (int ni = 0; ni < 2; ++ni) { f32x4 z = {0.f, 0.f, 0.f, 0.f}; oa[mi][ni] = z; }
    #pragma unroll
    for (int ks = 0; ks < 2; ++ks) {
        bf16x8 a0 = ld_frag(&a_l[0][0], wr * 32, ks * 32, 72);
        bf16x8 a1 = ld_frag(&a_l[0][0], wr * 32 + 16, ks * 32, 72);
        #pragma unroll
        for (int ni = 0; ni < 2; ++ni) {
            bf16x8 bb = ld_frag(&v_T[0][0], wc * 32 + ni * 16, ks * 32, 66);
            oa[0][ni] = MFMA16(a0, bb, oa[0][ni]);
            oa[1][ni] = MFMA16(a1, bb, oa[1][ni]);
        }
    }
    #pragma unroll
    for (int ks = 0; ks < 4; ++ks) {
        bf16x8 a0 = ld_frag(&pq_l[0][0], wr * 32, ks * 32, 136);
        bf16x8 a1 = ld_frag(&pq_l[0][0], wr * 32 + 16, ks * 32, 136);
        #pragma unroll
        for (int ni = 0; ni < 2; ++ni) {
            bf16x8 bb = ld_frag(&pkst_l[0][0], wc * 32 + ni * 16, ks * 32, 136);
            oa[0][ni] = MFMA16(a0, bb, oa[0][ni]);
            oa[1][ni] = MFMA16(a1, bb, oa[1][ni]);
        }
    }
    const int b_ = bh >> 3, h = bh & 7;
    #pragma unroll
    for (int mi = 0; mi < 2; ++mi)
        #pragma unroll
        for (int ni = 0; ni < 2; ++ni)
            #pragma unroll
            for (int i = 0; i < 4; ++i) {
                int row = wr * 32 + mi * 16 + ((lane >> 4) << 2) + i;
                int col = wc * 32 + ni * 16 + (lane & 15);
                float val = oa[mi][ni][i] * den[row];
                size_t oi = ((size_t)b_ * N_ + n0 + row) * 512 + h * 64 + col;
                o_bf[oi] = f2bf(val);
            }
}

// ---------------- output projection: out = o @ Woh^T + bo; 128x64 tiles ----------------
__global__ __launch_bounds__(256) void gemm_out(
    const short* __restrict__ o_bf, const short* __restrict__ Woh,
    const float* __restrict__ bo, float* __restrict__ out)
{
    __shared__ short Ah[128 * 32];
    __shared__ short Bh[64 * 32];
    const int t = threadIdx.x, lane = t & 63, wave = t >> 6;
    const int row0 = blockIdx.x * 128, col0 = blockIdx.y * 64;
    const int l_row = lane >> 2, l_col = (lane & 3) << 3;
    f32x4 acc[2][4];
    #pragma unroll
    for (int m = 0; m < 2; ++m)
        #pragma unroll
        for (int n = 0; n < 4; ++n) { f32x4 z = {0.f, 0.f, 0.f, 0.f}; acc[m][n] = z; }
    for (int k0 = 0; k0 < 512; k0 += 32) {
        #pragma unroll
        for (int sub = 0; sub < 2; ++sub) {
            int s = wave * 2 + sub;
            int gr = s * 16 + l_row;
            size_t ga = (size_t)(row0 + gr) * 512 + k0 + l_col;
            gl16(&Ah[s * 512], o_bf + ga);
        }
        {
            int gr = wave * 16 + l_row;
            size_t gb = (size_t)(col0 + gr) * 512 + k0 + l_col;
            gl16(&Bh[wave * 512], Woh + gb);
        }
        __syncthreads();
        bf16x8 bh[4];
        #pragma unroll
        for (int n = 0; n < 4; ++n) bh[n] = ld_frag(Bh, n * 16, 0, 32);
        #pragma unroll
        for (int m = 0; m < 2; ++m) {
            bf16x8 ah = ld_frag(Ah, wave * 32 + m * 16, 0, 32);
            #pragma unroll
            for (int n = 0; n < 4; ++n)
                acc[m][n] = MFMA16(ah, bh[n], acc[m][n]);
        }
        __syncthreads();
    }
    #pragma unroll
    for (int m = 0; m < 2; ++m)
        #pragma unroll
        for (int n = 0; n < 4; ++n)
            #pragma unroll
            for (int i = 0; i < 4; ++i) {
                int gr = row0 + wave * 32 + m * 16 + ((lane >> 4) << 2) + i;
                int gc = col0 + n * 16 + (lane & 15);
                out[(size_t)gr * 512 + gc] = acc[m][n][i] + bo[gc];
            }
}

extern "C" void kernel_launch(void* const* d_in, const int* in_sizes, int n_in,
                              void* d_out, int out_size, void* d_ws, size_t ws_size,
                              hipStream_t stream) {
    const float* x     = (const float*)d_in[0];
    const float* omega = (const float*)d_in[1];
    const float* Wq    = (const float*)d_in[2];
    const float* Wk    = (const float*)d_in[3];
    const float* Wv    = (const float*)d_in[4];
    const float* Wo    = (const float*)d_in[5];
    const float* bo    = (const float*)d_in[6];
    float* out = (float*)d_out;

    char* w = (char*)d_ws;
    short* xh   = (short*)(w);                                  // 0..4 MB
    short* Wch  = (short*)(w + (8ull  << 20));                  // 8..11 (3072x512 bf16)
    short* Wcl  = (short*)(w + (11ull << 20));                  // 11..14
    short* Woh  = (short*)(w + (14ull << 20));                  // 14..14.5
    short* phiq = (short*)(w + (15ull << 20));                  // 15..23
    short* pkloc= (short*)(w + (23ull << 20));                  // 23..31
    short* vbf  = (short*)(w + (31ull << 20));                  // 31..35
    short* Sbf  = (short*)(w + (35ull << 20));                  // 35..43
    short* STbf = (short*)(w + (43ull << 20));                  // 43..51
    short* obf  = (short*)(w + (51ull << 20));                  // 51..55
    float* ssqb = (float*)(w + (59ull << 20));                            // 128 KB
    float* pmaxp= (float*)(w + (59ull << 20) + (128ull << 10));           // 128 KB
    float* ksum = (float*)(w + (59ull << 20) + (256ull << 10));           // 256 KB
    float* kpre = (float*)(w + (59ull << 20) + (512ull << 10));           // 256 KB
    unsigned* gmaxu = (unsigned*)(w + (59ull << 20) + (768ull << 10));    // 4 B

    prep_all<<<2944, 256, 0, stream>>>(x, Wq, Wk, Wv, Wo, omega,
                                       xh, Wch, Wcl, Woh, gmaxu);
    gemm_fused<<<dim3(32, 24), 256, 0, stream>>>(xh, Wch, Wcl, phiq, pkloc,
                                                 vbf, ssqb, pmaxp);
    kmax_reduce<<<32, 256, 0, stream>>>(pmaxp, ssqb, gmaxu);
    chunk_kv_mfma<<<512, 256, 0, stream>>>(pkloc, ssqb, pmaxp, gmaxu, vbf, Sbf, ksum);
    prefix_scan<<<dim3(16, 5), 256, 0, stream>>>(Sbf, ksum, STbf, kpre);
    chunk_out_mfma<<<512, 256, 0, stream>>>(phiq, pkloc, ssqb, pmaxp, gmaxu,
                                            vbf, STbf, kpre, obf);
    gemm_out<<<dim3(32, 8), 256, 0, stream>>>(obf, Woh, bo, out);
}

// Round 11
// 168.269 us; speedup vs baseline: 1.0550x; 1.0126x over previous
//
#include <hip/hip_runtime.h>
#include <math.h>

#define B_ 2
#define N_ 2048
#define DIM_ 512
#define H_ 8
#define D_ 64
#define M_ 128
#define NC_ 32
#define C_ 64

#define INV_SQRT_M 0.08838834764831845f
#define QK_SCALE 0.35355339059327373f

typedef __attribute__((ext_vector_type(8))) short bf16x8;
typedef __attribute__((ext_vector_type(4))) short bf16x4;
typedef __attribute__((ext_vector_type(4))) float f32x4;

#define MFMA16(a, b, c) __builtin_amdgcn_mfma_f32_16x16x32_bf16((a), (b), (c), 0, 0, 0)

__device__ __forceinline__ short f2bf(float f) {
    union { float f; unsigned u; } x; x.f = f;
    unsigned r = (x.u + 0x7FFFu + ((x.u >> 16) & 1u)) >> 16;
    return (short)r;
}
__device__ __forceinline__ float bf2f(short s) {
    union { unsigned u; float f; } x; x.u = ((unsigned)(unsigned short)s) << 16;
    return x.f;
}
// monotone float<->uint encoding for atomicMax on floats (incl. negatives)
__device__ __forceinline__ unsigned encf(float f) {
    unsigned u = __float_as_uint(f);
    return (u & 0x80000000u) ? ~u : (u | 0x80000000u);
}
__device__ __forceinline__ float decf(unsigned e) {
    unsigned u = (e & 0x80000000u) ? (e & 0x7FFFFFFFu) : ~e;
    return __uint_as_float(u);
}

// async global->LDS 16B copy: LDS dst = (wave-uniform base) + lane*16
__device__ __forceinline__ void gl16(void* lds, const void* g) {
    __builtin_amdgcn_global_load_lds(
        (const __attribute__((address_space(1))) unsigned int*)g,
        (__attribute__((address_space(3))) unsigned int*)lds,
        16, 0, 0);
}

// fragment load from row-major LDS tile [rows][ldk] bf16 (A or B^T form)
__device__ __forceinline__ bf16x8 ld_frag(const short* base, int row0, int k0, int ldk) {
    const int lane = threadIdx.x & 63;
    return *(const bf16x8*)(base + (row0 + (lane & 15)) * ldk + k0 + ((lane >> 4) << 3));
}

// ---------------- prep (merged): x->bf16 hi; hi-only Wk/Wv/Wo; omega@W rows hi/lo; gmax init ----------------
__global__ __launch_bounds__(256) void prep_all(
    const float* __restrict__ x, const float* __restrict__ Wq, const float* __restrict__ Wk,
    const float* __restrict__ Wv, const float* __restrict__ Wo, const float* __restrict__ omega,
    short* __restrict__ xh,
    short* __restrict__ Wch, short* __restrict__ Wcl,
    short* __restrict__ Woh, unsigned* __restrict__ gmaxu)
{
    __shared__ float Ws[64][65];
    __shared__ float om[128][64];
    const int t = threadIdx.x;
    const int bid = blockIdx.x;
    if (bid < 2816) {
        int i4 = bid * 256 + t;
        if (i4 == 0) gmaxu[0] = 0u;   // < enc of any real float
        if (i4 < 524288) {
            float4 v = *(const float4*)(x + (size_t)i4 * 4);
            bf16x4 hi;
            hi[0] = f2bf(v.x); hi[1] = f2bf(v.y);
            hi[2] = f2bf(v.z); hi[3] = f2bf(v.w);
            *(bf16x4*)(xh + (size_t)i4 * 4) = hi;
        } else {
            int r = i4 - 524288;
            int widx = r >> 16, off4 = r & 65535;
            const float* src; short* dst; float sc;
            if (widx == 0)      { src = Wk; dst = Wch;          sc = QK_SCALE; }
            else if (widx == 1) { src = Wv; dst = Wch + 262144; sc = 1.f; }
            else                { src = Wo; dst = Woh;          sc = 1.f; }
            float4 v = *(const float4*)(src + (size_t)off4 * 4);
            bf16x4 hi;
            hi[0] = f2bf(v.x * sc); hi[1] = f2bf(v.y * sc);
            hi[2] = f2bf(v.z * sc); hi[3] = f2bf(v.w * sc);
            *(bf16x4*)(dst + (size_t)off4 * 4) = hi;
        }
    } else {
        // omega @ (W*scale) -> Wcomb rows 1024..3072, hi/lo
        const int bx = bid - 2816;
        const int qk = bx >> 6, h = (bx >> 3) & 7, cb = bx & 7;
        const int col0 = cb * 64;
        const float* W = qk ? Wk : Wq;
        for (int i = t; i < 64 * 64; i += 256) {
            int d = i >> 6, c = i & 63;
            Ws[d][c] = W[(size_t)(h * 64 + d) * 512 + col0 + c] * QK_SCALE;
        }
        for (int i = t; i < 128 * 64; i += 256) om[i >> 6][i & 63] = omega[i];
        __syncthreads();
        const int lane = t & 63, w = t >> 6;
        const int c = col0 + lane;
        float Wcol[64];
        #pragma unroll
        for (int d = 0; d < 64; ++d) Wcol[d] = Ws[d][lane];
        for (int mi = 0; mi < 32; ++mi) {
            int m = w * 32 + mi;
            float acc = 0.f;
            #pragma unroll
            for (int d = 0; d < 64; d += 4) {
                float4 o4 = *(const float4*)&om[m][d];
                acc += o4.x * Wcol[d] + o4.y * Wcol[d+1] + o4.z * Wcol[d+2] + o4.w * Wcol[d+3];
            }
            int row = 1024 + qk * 1024 + h * 128 + m;
            short hi = f2bf(acc);
            Wch[(size_t)row * 512 + c] = hi;
            Wcl[(size_t)row * 512 + c] = f2bf(acc - bf2f(hi));
        }
    }
}

// ---------------- fused GEMM: [4096 x 3072] = x @ Wcomb^T ----------------
// cols [0,512) k->ssq (1-pass); [512,1024) v->bf16 (1-pass);
//      [1024,2048) projq -> phiq bf16 (2-pass hi/lo-B, in-epilogue row-max + exp);
//      [2048,3072) projk -> pk_local bf16 + pmaxp (2-pass)
__global__ __launch_bounds__(256) void gemm_fused(
    const short* __restrict__ xh,
    const short* __restrict__ Wch, const short* __restrict__ Wcl,
    short* __restrict__ phiq, short* __restrict__ pkloc,
    short* __restrict__ vbf, float* __restrict__ ssqbuf, float* __restrict__ pmaxp)
{
    __shared__ short Ah[128 * 32];
    __shared__ short Bh[128 * 32];
    __shared__ short Bl[128 * 32];
    __shared__ float rmx[128][2];
    const int t = threadIdx.x, lane = t & 63, wave = t >> 6;
    const int wr = wave >> 1, wc = wave & 1;
    const int row0 = blockIdx.x * 128;
    const int by = blockIdx.y;
    const int col0 = by * 128;
    const int l_row = lane >> 2, l_col = (lane & 3) << 3;
    const bool two = (by >= 8);
    f32x4 acc[4][4];
    #pragma unroll
    for (int m = 0; m < 4; ++m)
        #pragma unroll
        for (int n = 0; n < 4; ++n) { f32x4 z = {0.f, 0.f, 0.f, 0.f}; acc[m][n] = z; }
    for (int k0 = 0; k0 < 512; k0 += 32) {
        #pragma unroll
        for (int sub = 0; sub < 2; ++sub) {
            int s = wave * 2 + sub;
            int gr = s * 16 + l_row;
            size_t ga = (size_t)(row0 + gr) * 512 + k0 + l_col;
            size_t gb = (size_t)(col0 + gr) * 512 + k0 + l_col;
            gl16(&Ah[s * 512], xh + ga);
            gl16(&Bh[s * 512], Wch + gb);
            if (two) gl16(&Bl[s * 512], Wcl + gb);
        }
        __syncthreads();
        if (two) {
            bf16x8 bh[4], bl[4];
            #pragma unroll
            for (int n = 0; n < 4; ++n) {
                bh[n] = ld_frag(Bh, wc * 64 + n * 16, 0, 32);
                bl[n] = ld_frag(Bl, wc * 64 + n * 16, 0, 32);
            }
            #pragma unroll
            for (int m = 0; m < 4; ++m) {
                bf16x8 ah = ld_frag(Ah, wr * 64 + m * 16, 0, 32);
                #pragma unroll
                for (int n = 0; n < 4; ++n) {
                    acc[m][n] = MFMA16(ah, bl[n], acc[m][n]);
                    acc[m][n] = MFMA16(ah, bh[n], acc[m][n]);
                }
            }
        } else {
            bf16x8 bh[4];
            #pragma unroll
            for (int n = 0; n < 4; ++n) bh[n] = ld_frag(Bh, wc * 64 + n * 16, 0, 32);
            #pragma unroll
            for (int m = 0; m < 4; ++m) {
                bf16x8 ah = ld_frag(Ah, wr * 64 + m * 16, 0, 32);
                #pragma unroll
                for (int n = 0; n < 4; ++n) acc[m][n] = MFMA16(ah, bh[n], acc[m][n]);
            }
        }
        __syncthreads();
    }
    if (by < 4) {
        // k ssq: head = by*2+wc, per-wave 64 cols = 1 head
        const int head = by * 2 + wc;
        #pragma unroll
        for (int m = 0; m < 4; ++m)
            #pragma unroll
            for (int i = 0; i < 4; ++i) {
                float s = 0.f;
                #pragma unroll
                for (int n = 0; n < 4; ++n) { float v2 = acc[m][n][i]; s += v2 * v2; }
                s += __shfl_xor(s, 1); s += __shfl_xor(s, 2);
                s += __shfl_xor(s, 4); s += __shfl_xor(s, 8);
                if ((lane & 15) == 0) {
                    int row = row0 + wr * 64 + m * 16 + ((lane >> 4) << 2) + i;
                    int b = row >> 11, nn = row & 2047;
                    ssqbuf[(b * 8 + head) * 2048 + nn] = s;
                }
            }
    } else if (by < 8) {
        #pragma unroll
        for (int m = 0; m < 4; ++m)
            #pragma unroll
            for (int n = 0; n < 4; ++n)
                #pragma unroll
                for (int i = 0; i < 4; ++i) {
                    int row = row0 + wr * 64 + m * 16 + ((lane >> 4) << 2) + i;
                    int gc = col0 + wc * 64 + n * 16 + (lane & 15);
                    int c = gc - 512, h = c >> 6, d = c & 63;
                    int b = row >> 11, nn = row & 2047;
                    vbf[((size_t)(b * 8 + h) * 2048 + nn) * 64 + d] = f2bf(acc[m][n][i]);
                }
    } else {
        const bool isq = (by < 16);
        const int h = isq ? (by - 8) : (by - 16);
        // full-row max: per-wave 64-col max -> LDS exchange across wc
        #pragma unroll
        for (int m = 0; m < 4; ++m)
            #pragma unroll
            for (int i = 0; i < 4; ++i) {
                float mx = fmaxf(fmaxf(acc[m][0][i], acc[m][1][i]),
                                 fmaxf(acc[m][2][i], acc[m][3][i]));
                mx = fmaxf(mx, __shfl_xor(mx, 1));
                mx = fmaxf(mx, __shfl_xor(mx, 2));
                mx = fmaxf(mx, __shfl_xor(mx, 4));
                mx = fmaxf(mx, __shfl_xor(mx, 8));
                if ((lane & 15) == 0)
                    rmx[wr * 64 + m * 16 + ((lane >> 4) << 2) + i][wc] = mx;
            }
        __syncthreads();
        short* dst = isq ? phiq : pkloc;
        #pragma unroll
        for (int m = 0; m < 4; ++m)
            #pragma unroll
            for (int i = 0; i < 4; ++i) {
                int lr = wr * 64 + m * 16 + ((lane >> 4) << 2) + i;
                float fm = fmaxf(rmx[lr][0], rmx[lr][1]);
                int row = row0 + lr;
                int b = row >> 11, nn = row & 2047;
                size_t g = (size_t)(b * 8 + h) * 2048 + nn;
                #pragma unroll
                for (int n = 0; n < 4; ++n) {
                    int mc = wc * 64 + n * 16 + (lane & 15);
                    float e = __expf(acc[m][n][i] - fm);
                    float val = isq ? (e * INV_SQRT_M + 1e-4f) : e;
                    dst[g * 128 + mc] = f2bf(val);
                }
                if (!isq && wc == 0 && (lane & 15) == 0) pmaxp[g] = fm;
            }
    }
}

// ---------------- global key-max: 32 blocks, 32 atomics ----------------
__global__ __launch_bounds__(256) void kmax_reduce(const float* __restrict__ pmaxp,
    const float* __restrict__ ssqbuf, unsigned* __restrict__ gmaxu)
{
    float m = -3.402823466e38f;
    for (int g = blockIdx.x * 256 + threadIdx.x; g < 32768; g += 8192)
        m = fmaxf(m, pmaxp[g] - 0.5f * ssqbuf[g]);
    #pragma unroll
    for (int off = 1; off < 64; off <<= 1) m = fmaxf(m, __shfl_xor(m, off));
    __shared__ float w[4];
    if ((threadIdx.x & 63) == 0) w[threadIdx.x >> 6] = m;
    __syncthreads();
    if (threadIdx.x == 0)
        atomicMax(gmaxu, encf(fmaxf(fmaxf(w[0], w[1]), fmaxf(w[2], w[3]))));
}

// ---------------- per-chunk KV sums: ST[d][m] = sum_n v[n][d] pk[n][m] (bf16 out) ----------------
// pk and v staged TRANSPOSED in LDS so all MFMA fragment loads are contiguous ds_read_b128
__global__ __launch_bounds__(256) void chunk_kv_mfma(
    const short* __restrict__ pkloc, const float* __restrict__ ssqbuf,
    const float* __restrict__ pmaxp, const unsigned* __restrict__ gmaxu,
    const short* __restrict__ v_bf, short* __restrict__ Sbf, float* __restrict__ ksum)
{
    __shared__ short pk_T[128][66];   // [m][n]
    __shared__ short v_T[64][66];     // [d][n]
    __shared__ float srow[64];
    const int t = threadIdx.x, lane = t & 63, wave = t >> 6;
    const int wr = wave >> 1, wc = wave & 1;
    const int bh = blockIdx.x >> 5, j = blockIdx.x & 31;
    const int n0 = j << 6;
    const float g = decf(gmaxu[0]);
    if (t < 64) {
        int gr = bh * 2048 + n0 + t;
        srow[t] = __expf(pmaxp[gr] - 0.5f * ssqbuf[gr] - g) * INV_SQRT_M;
    }
    __syncthreads();
    #pragma unroll
    for (int it = 0; it < 4; ++it) {
        int idx = t + it * 256;
        int r = idx >> 4, c8 = (idx & 15) << 3;
        bf16x8 raw = *(const bf16x8*)(pkloc + ((size_t)(bh * 2048 + n0 + r)) * 128 + c8);
        float s = srow[r];
        #pragma unroll
        for (int u = 0; u < 8; ++u) pk_T[c8 + u][r] = f2bf(bf2f(raw[u]) * s + 1e-4f);
    }
    #pragma unroll
    for (int it = 0; it < 2; ++it) {
        int idx = t + it * 256;
        int r = idx >> 3, c8 = (idx & 7) << 3;
        bf16x8 raw = *(const bf16x8*)(v_bf + ((size_t)(bh * 2048 + n0 + r)) * 64 + c8);
        #pragma unroll
        for (int u = 0; u < 8; ++u) v_T[c8 + u][r] = raw[u];
    }
    __syncthreads();
    f32x4 acc[2][4];
    #pragma unroll
    for (int mi = 0; mi < 2; ++mi)
        #pragma unroll
        for (int ni = 0; ni < 4; ++ni) { f32x4 z = {0.f, 0.f, 0.f, 0.f}; acc[mi][ni] = z; }
    #pragma unroll
    for (int ks = 0; ks < 2; ++ks) {
        bf16x8 a0 = ld_frag(&v_T[0][0], wr * 32, ks * 32, 66);
        bf16x8 a1 = ld_frag(&v_T[0][0], wr * 32 + 16, ks * 32, 66);
        #pragma unroll
        for (int ni = 0; ni < 4; ++ni) {
            bf16x8 bb = ld_frag(&pk_T[0][0], wc * 64 + ni * 16, ks * 32, 66);
            acc[0][ni] = MFMA16(a0, bb, acc[0][ni]);
            acc[1][ni] = MFMA16(a1, bb, acc[1][ni]);
        }
    }
    const size_t sbase = ((size_t)blockIdx.x) << 13;
    #pragma unroll
    for (int mi = 0; mi < 2; ++mi)
        #pragma unroll
        for (int ni = 0; ni < 4; ++ni)
            #pragma unroll
            for (int i = 0; i < 4; ++i) {
                int row = wr * 32 + mi * 16 + ((lane >> 4) << 2) + i;
                int col = wc * 64 + ni * 16 + (lane & 15);
                Sbf[sbase + (size_t)row * 128 + col] = f2bf(acc[mi][ni][i]);
            }
    if (t < 128) {
        float s = 0.f;
        #pragma unroll
        for (int n8 = 0; n8 < 64; n8 += 8) {
            bf16x8 v = *(const bf16x8*)&pk_T[t][n8];
            #pragma unroll
            for (int u = 0; u < 8; ++u) s += bf2f(v[u]);
        }
        ksum[((size_t)blockIdx.x) * 128 + t] = s;
    }
}

// ---------------- exclusive prefix over chunks (vectorized bf16x8 / float4) ----------------
__global__ __launch_bounds__(256) void prefix_scan(const short* __restrict__ Sbf,
    const float* __restrict__ ksum, short* __restrict__ STbf, float* __restrict__ kpre)
{
    const int bh = blockIdx.x, y = blockIdx.y, t = threadIdx.x;
    if (y < 4) {
        int e8 = (y * 256 + t) * 8;   // within 8192-elem chunk
        size_t base = (size_t)bh * NC_ * 8192 + e8;
        float run[8] = {0.f, 0.f, 0.f, 0.f, 0.f, 0.f, 0.f, 0.f};
        #pragma unroll
        for (int j = 0; j < NC_; ++j) {
            bf16x8 v = *(const bf16x8*)(Sbf + base + (size_t)j * 8192);
            bf16x8 o;
            #pragma unroll
            for (int u = 0; u < 8; ++u) { o[u] = f2bf(run[u]); run[u] += bf2f(v[u]); }
            *(bf16x8*)(STbf + base + (size_t)j * 8192) = o;
        }
    } else if (t < 32) {
        size_t base = (size_t)bh * NC_ * 128 + t * 4;
        float r0 = 0.f, r1 = 0.f, r2 = 0.f, r3 = 0.f;
        #pragma unroll
        for (int j = 0; j < NC_; ++j) {
            float4 v = *(const float4*)(ksum + base + (size_t)j * 128);
            float4 o; o.x = r0; o.y = r1; o.z = r2; o.w = r3;
            *(float4*)(kpre + base + (size_t)j * 128) = o;
            r0 += v.x; r1 += v.y; r2 += v.z; r3 += v.w;
        }
    }
}

// ---------------- per-chunk output (MFMA); o written bf16 (no lo split) ----------------
__global__ __launch_bounds__(256) void chunk_out_mfma(
    const short* __restrict__ phi_q, const short* __restrict__ pkloc,
    const float* __restrict__ ssqbuf, const float* __restrict__ pmaxp,
    const unsigned* __restrict__ gmaxu,
    const short* __restrict__ v_bf, const short* __restrict__ STbf,
    const float* __restrict__ kpre, short* __restrict__ o_bf)
{
    __shared__ short pq_l[64][136];
    __shared__ short pkst_l[64][136];
    __shared__ short v_T[64][66];     // [d][n]
    __shared__ short a_l[64][72];
    __shared__ float rsum[64][8];
    __shared__ float den[64];
    __shared__ float ksp_l[128];
    __shared__ float srow[64];
    const int t = threadIdx.x, lane = t & 63, wave = t >> 6;
    const int wr = wave >> 1, wc = wave & 1;
    const int bh = blockIdx.x >> 5, j = blockIdx.x & 31;
    const int n0 = j << 6;
    const size_t prow = (size_t)bh * N_ + n0;
    const float g = decf(gmaxu[0]);
    if (t < 64) {
        int gr = bh * 2048 + n0 + t;
        srow[t] = __expf(pmaxp[gr] - 0.5f * ssqbuf[gr] - g) * INV_SQRT_M;
    }
    if (t < 128) ksp_l[t] = kpre[((size_t)bh * NC_ + j) * 128 + t];
    __syncthreads();
    #pragma unroll
    for (int it = 0; it < 4; ++it) {
        int idx = t + it * 256;
        int r = idx >> 4, c8 = (idx & 15) << 3;
        *(bf16x8*)&pq_l[r][c8] = *(const bf16x8*)(phi_q + (prow + r) * 128 + c8);
        bf16x8 raw = *(const bf16x8*)(pkloc + (prow + r) * 128 + c8);
        float s = srow[r];
        bf16x8 o;
        #pragma unroll
        for (int u = 0; u < 8; ++u) o[u] = f2bf(bf2f(raw[u]) * s + 1e-4f);
        *(bf16x8*)&pkst_l[r][c8] = o;
    }
    #pragma unroll
    for (int it = 0; it < 2; ++it) {
        int idx = t + it * 256;
        int r = idx >> 3, c8 = (idx & 7) << 3;
        bf16x8 raw = *(const bf16x8*)(v_bf + (prow + r) * 64 + c8);
        #pragma unroll
        for (int u = 0; u < 8; ++u) v_T[c8 + u][r] = raw[u];
    }
    __syncthreads();
    f32x4 qk[2][2];
    #pragma unroll
    for (int mi = 0; mi < 2; ++mi)
        #pragma unroll
        for (int ni = 0; ni < 2; ++ni) { f32x4 z = {0.f, 0.f, 0.f, 0.f}; qk[mi][ni] = z; }
    #pragma unroll
    for (int ks = 0; ks < 4; ++ks) {
        bf16x8 a0 = ld_frag(&pq_l[0][0], wr * 32, ks * 32, 136);
        bf16x8 a1 = ld_frag(&pq_l[0][0], wr * 32 + 16, ks * 32, 136);
        bf16x8 b0 = ld_frag(&pkst_l[0][0], wc * 32, ks * 32, 136);
        bf16x8 b1 = ld_frag(&pkst_l[0][0], wc * 32 + 16, ks * 32, 136);
        qk[0][0] = MFMA16(a0, b0, qk[0][0]);
        qk[0][1] = MFMA16(a0, b1, qk[0][1]);
        qk[1][0] = MFMA16(a1, b0, qk[1][0]);
        qk[1][1] = MFMA16(a1, b1, qk[1][1]);
    }
    #pragma unroll
    for (int mi = 0; mi < 2; ++mi)
        #pragma unroll
        for (int i = 0; i < 4; ++i) {
            int row = wr * 32 + mi * 16 + ((lane >> 4) << 2) + i;
            float part = 0.f;
            #pragma unroll
            for (int ni = 0; ni < 2; ++ni) {
                int col = wc * 32 + ni * 16 + (lane & 15);
                float val = (col <= row) ? qk[mi][ni][i] : 0.f;
                a_l[row][col] = f2bf(val);
                part += val;
            }
            part += __shfl_xor(part, 1);
            part += __shfl_xor(part, 2);
            part += __shfl_xor(part, 4);
            part += __shfl_xor(part, 8);
            if ((lane & 15) == 0) rsum[row][wc] = part;
        }
    {
        int row = t & 63, qq = t >> 6;
        float s = 0.f;
        #pragma unroll
        for (int m = 0; m < 32; ++m) s += bf2f(pq_l[row][qq * 32 + m]) * ksp_l[qq * 32 + m];
        rsum[row][4 + qq] = s;
    }
    __syncthreads();
    #pragma unroll
    for (int it = 0; it < 4; ++it) {
        int idx = t + it * 256;
        int r = idx >> 4, c8 = (idx & 15) << 3;
        *(bf16x8*)&pkst_l[r][c8] =
            *(const bf16x8*)(STbf + (((size_t)bh * NC_ + j) << 13) + r * 128 + c8);
    }
    if (t < 64) {
        float s = rsum[t][0] + rsum[t][1] + rsum[t][4] + rsum[t][5] + rsum[t][6] + rsum[t][7];
        den[t] = 1.0f / (s + 1e-6f);
    }
    __syncthreads();
    f32x4 oa[2][2];
    #pragma unroll
    for (int mi = 0; mi < 2; ++mi)
        #pragma unroll
        for (int ni = 0; ni < 2; ++ni) { f32x4 z = {0.f, 0.f, 0.f, 0.f}; oa[mi][ni] = z; }
    #pragma unroll
    for (int ks = 0; ks < 2; ++ks) {
        bf16x8 a0 = ld_frag(&a_l[0][0], wr * 32, ks * 32, 72);
        bf16x8 a1 = ld_frag(&a_l[0][0], wr * 32 + 16, ks * 32, 72);
        #pragma unroll
        for (int ni = 0; ni < 2; ++ni) {
            bf16x8 bb = ld_frag(&v_T[0][0], wc * 32 + ni * 16, ks * 32, 66);
            oa[0][ni] = MFMA16(a0, bb, oa[0][ni]);
            oa[1][ni] = MFMA16(a1, bb, oa[1][ni]);
        }
    }
    #pragma unroll
    for (int ks = 0; ks < 4; ++ks) {
        bf16x8 a0 = ld_frag(&pq_l[0][0], wr * 32, ks * 32, 136);
        bf16x8 a1 = ld_frag(&pq_l[0][0], wr * 32 + 16, ks * 32, 136);
        #pragma unroll
        for (int ni = 0; ni < 2; ++ni) {
            bf16x8 bb = ld_frag(&pkst_l[0][0], wc * 32 + ni * 16, ks * 32, 136);
            oa[0][ni] = MFMA16(a0, bb, oa[0][ni]);
            oa[1][ni] = MFMA16(a1, bb, oa[1][ni]);
        }
    }
    const int b_ = bh >> 3, h = bh & 7;
    #pragma unroll
    for (int mi = 0; mi < 2; ++mi)
        #pragma unroll
        for (int ni = 0; ni < 2; ++ni)
            #pragma unroll
            for (int i = 0; i < 4; ++i) {
                int row = wr * 32 + mi * 16 + ((lane >> 4) << 2) + i;
                int col = wc * 32 + ni * 16 + (lane & 15);
                float val = oa[mi][ni][i] * den[row];
                size_t oi = ((size_t)b_ * N_ + n0 + row) * 512 + h * 64 + col;
                o_bf[oi] = f2bf(val);
            }
}

// ---------------- output projection: out = o @ Woh^T + bo; 128x64 tiles, 8 waves ----------------
__global__ __launch_bounds__(512) void gemm_out(
    const short* __restrict__ o_bf, const short* __restrict__ Woh,
    const float* __restrict__ bo, float* __restrict__ out)
{
    __shared__ short Ah[128 * 32];
    __shared__ short Bh[64 * 32];
    const int t = threadIdx.x, lane = t & 63, wave = t >> 6;   // 8 waves
    const int row0 = blockIdx.x * 128, col0 = blockIdx.y * 64;
    const int l_row = lane >> 2, l_col = (lane & 3) << 3;
    f32x4 acc[4];
    #pragma unroll
    for (int n = 0; n < 4; ++n) { f32x4 z = {0.f, 0.f, 0.f, 0.f}; acc[n] = z; }
    for (int k0 = 0; k0 < 512; k0 += 32) {
        {
            int gr = wave * 16 + l_row;
            size_t ga = (size_t)(row0 + gr) * 512 + k0 + l_col;
            gl16(&Ah[wave * 512], o_bf + ga);
        }
        if (wave < 4) {
            int gr = wave * 16 + l_row;
            size_t gb = (size_t)(col0 + gr) * 512 + k0 + l_col;
            gl16(&Bh[wave * 512], Woh + gb);
        }
        __syncthreads();
        bf16x8 ah = ld_frag(Ah, wave * 16, 0, 32);
        #pragma unroll
        for (int n = 0; n < 4; ++n) {
            bf16x8 bh = ld_frag(Bh, n * 16, 0, 32);
            acc[n] = MFMA16(ah, bh, acc[n]);
        }
        __syncthreads();
    }
    #pragma unroll
    for (int n = 0; n < 4; ++n)
        #pragma unroll
        for (int i = 0; i < 4; ++i) {
            int gr = row0 + wave * 16 + ((lane >> 4) << 2) + i;
            int gc = col0 + n * 16 + (lane & 15);
            out[(size_t)gr * 512 + gc] = acc[n][i] + bo[gc];
        }
}

extern "C" void kernel_launch(void* const* d_in, const int* in_sizes, int n_in,
                              void* d_out, int out_size, void* d_ws, size_t ws_size,
                              hipStream_t stream) {
    const float* x     = (const float*)d_in[0];
    const float* omega = (const float*)d_in[1];
    const float* Wq    = (const float*)d_in[2];
    const float* Wk    = (const float*)d_in[3];
    const float* Wv    = (const float*)d_in[4];
    const float* Wo    = (const float*)d_in[5];
    const float* bo    = (const float*)d_in[6];
    float* out = (float*)d_out;

    char* w = (char*)d_ws;
    short* xh   = (short*)(w);                                  // 0..4 MB
    short* Wch  = (short*)(w + (8ull  << 20));                  // 8..11 (3072x512 bf16)
    short* Wcl  = (short*)(w + (11ull << 20));                  // 11..14
    short* Woh  = (short*)(w + (14ull << 20));                  // 14..14.5
    short* phiq = (short*)(w + (15ull << 20));                  // 15..23
    short* pkloc= (short*)(w + (23ull << 20));                  // 23..31
    short* vbf  = (short*)(w + (31ull << 20));                  // 31..35
    short* Sbf  = (short*)(w + (35ull << 20));                  // 35..43
    short* STbf = (short*)(w + (43ull << 20));                  // 43..51
    short* obf  = (short*)(w + (51ull << 20));                  // 51..55
    float* ssqb = (float*)(w + (59ull << 20));                            // 128 KB
    float* pmaxp= (float*)(w + (59ull << 20) + (128ull << 10));           // 128 KB
    float* ksum = (float*)(w + (59ull << 20) + (256ull << 10));           // 256 KB
    float* kpre = (float*)(w + (59ull << 20) + (512ull << 10));           // 256 KB
    unsigned* gmaxu = (unsigned*)(w + (59ull << 20) + (768ull << 10));    // 4 B

    prep_all<<<2944, 256, 0, stream>>>(x, Wq, Wk, Wv, Wo, omega,
                                       xh, Wch, Wcl, Woh, gmaxu);
    gemm_fused<<<dim3(32, 24), 256, 0, stream>>>(xh, Wch, Wcl, phiq, pkloc,
                                                 vbf, ssqb, pmaxp);
    kmax_reduce<<<32, 256, 0, stream>>>(pmaxp, ssqb, gmaxu);
    chunk_kv_mfma<<<512, 256, 0, stream>>>(pkloc, ssqb, pmaxp, gmaxu, vbf, Sbf, ksum);
    prefix_scan<<<dim3(16, 5), 256, 0, stream>>>(Sbf, ksum, STbf, kpre);
    chunk_out_mfma<<<512, 256, 0, stream>>>(phiq, pkloc, ssqb, pmaxp, gmaxu,
                                            vbf, STbf, kpre, obf);
    gemm_out<<<dim3(32, 8), 512, 0, stream>>>(obf, Woh, bo, out);
}

// Round 12
// 154.737 us; speedup vs baseline: 1.1473x; 1.0875x over previous
//
#include <hip/hip_runtime.h>
#include <math.h>

#define B_ 2
#define N_ 2048
#define DIM_ 512
#define H_ 8
#define D_ 64
#define M_ 128
#define NC_ 32
#define C_ 64

#define INV_SQRT_M 0.08838834764831845f
#define QK_SCALE 0.35355339059327373f

typedef __attribute__((ext_vector_type(8))) short bf16x8;
typedef __attribute__((ext_vector_type(4))) short bf16x4;
typedef __attribute__((ext_vector_type(4))) float f32x4;

#define MFMA16(a, b, c) __builtin_amdgcn_mfma_f32_16x16x32_bf16((a), (b), (c), 0, 0, 0)

__device__ __forceinline__ short f2bf(float f) {
    union { float f; unsigned u; } x; x.f = f;
    unsigned r = (x.u + 0x7FFFu + ((x.u >> 16) & 1u)) >> 16;
    return (short)r;
}
__device__ __forceinline__ float bf2f(short s) {
    union { unsigned u; float f; } x; x.u = ((unsigned)(unsigned short)s) << 16;
    return x.f;
}
// monotone float<->uint encoding for atomicMax on floats (incl. negatives)
__device__ __forceinline__ unsigned encf(float f) {
    unsigned u = __float_as_uint(f);
    return (u & 0x80000000u) ? ~u : (u | 0x80000000u);
}
__device__ __forceinline__ float decf(unsigned e) {
    unsigned u = (e & 0x80000000u) ? (e & 0x7FFFFFFFu) : ~e;
    return __uint_as_float(u);
}

// async global->LDS 16B copy: LDS dst = (wave-uniform base) + lane*16
__device__ __forceinline__ void gl16(void* lds, const void* g) {
    __builtin_amdgcn_global_load_lds(
        (const __attribute__((address_space(1))) unsigned int*)g,
        (__attribute__((address_space(3))) unsigned int*)lds,
        16, 0, 0);
}

// fragment load from row-major LDS tile [rows][ldk] bf16 (A or B^T form)
__device__ __forceinline__ bf16x8 ld_frag(const short* base, int row0, int k0, int ldk) {
    const int lane = threadIdx.x & 63;
    return *(const bf16x8*)(base + (row0 + (lane & 15)) * ldk + k0 + ((lane >> 4) << 3));
}

// ---------------- prep (merged): x->bf16; Wk/Wv/Wo->bf16; omega@W rows; gmax init ----------------
__global__ __launch_bounds__(256) void prep_all(
    const float* __restrict__ x, const float* __restrict__ Wq, const float* __restrict__ Wk,
    const float* __restrict__ Wv, const float* __restrict__ Wo, const float* __restrict__ omega,
    short* __restrict__ xh,
    short* __restrict__ Wch,
    short* __restrict__ Woh, unsigned* __restrict__ gmaxu)
{
    __shared__ float Ws[64][65];
    __shared__ float om[128][64];
    const int t = threadIdx.x;
    const int bid = blockIdx.x;
    if (bid < 2816) {
        int i4 = bid * 256 + t;
        if (i4 == 0) gmaxu[0] = 0u;   // < enc of any real float
        if (i4 < 524288) {
            float4 v = *(const float4*)(x + (size_t)i4 * 4);
            bf16x4 hi;
            hi[0] = f2bf(v.x); hi[1] = f2bf(v.y);
            hi[2] = f2bf(v.z); hi[3] = f2bf(v.w);
            *(bf16x4*)(xh + (size_t)i4 * 4) = hi;
        } else {
            int r = i4 - 524288;
            int widx = r >> 16, off4 = r & 65535;
            const float* src; short* dst; float sc;
            if (widx == 0)      { src = Wk; dst = Wch;          sc = QK_SCALE; }
            else if (widx == 1) { src = Wv; dst = Wch + 262144; sc = 1.f; }
            else                { src = Wo; dst = Woh;          sc = 1.f; }
            float4 v = *(const float4*)(src + (size_t)off4 * 4);
            bf16x4 hi;
            hi[0] = f2bf(v.x * sc); hi[1] = f2bf(v.y * sc);
            hi[2] = f2bf(v.z * sc); hi[3] = f2bf(v.w * sc);
            *(bf16x4*)(dst + (size_t)off4 * 4) = hi;
        }
    } else {
        // omega @ (W*scale) -> Wcomb rows 1024..3072 (bf16)
        const int bx = bid - 2816;
        const int qk = bx >> 6, h = (bx >> 3) & 7, cb = bx & 7;
        const int col0 = cb * 64;
        const float* W = qk ? Wk : Wq;
        for (int i = t; i < 64 * 64; i += 256) {
            int d = i >> 6, c = i & 63;
            Ws[d][c] = W[(size_t)(h * 64 + d) * 512 + col0 + c] * QK_SCALE;
        }
        for (int i = t; i < 128 * 64; i += 256) om[i >> 6][i & 63] = omega[i];
        __syncthreads();
        const int lane = t & 63, w = t >> 6;
        const int c = col0 + lane;
        float Wcol[64];
        #pragma unroll
        for (int d = 0; d < 64; ++d) Wcol[d] = Ws[d][lane];
        for (int mi = 0; mi < 32; ++mi) {
            int m = w * 32 + mi;
            float acc = 0.f;
            #pragma unroll
            for (int d = 0; d < 64; d += 4) {
                float4 o4 = *(const float4*)&om[m][d];
                acc += o4.x * Wcol[d] + o4.y * Wcol[d+1] + o4.z * Wcol[d+2] + o4.w * Wcol[d+3];
            }
            int row = 1024 + qk * 1024 + h * 128 + m;
            Wch[(size_t)row * 512 + c] = f2bf(acc);
        }
    }
}

// ---------------- fused GEMM: [4096 x 3072] = x @ Wcomb^T (uniform 1-pass bf16) ----------------
// cols [0,512) k->ssq; [512,1024) v->bf16;
//      [1024,2048) projq -> phiq bf16 (in-epilogue row-max + exp);
//      [2048,3072) projk -> pk_local bf16 + pmaxp
__global__ __launch_bounds__(256) void gemm_fused(
    const short* __restrict__ xh,
    const short* __restrict__ Wch,
    short* __restrict__ phiq, short* __restrict__ pkloc,
    short* __restrict__ vbf, float* __restrict__ ssqbuf, float* __restrict__ pmaxp)
{
    __shared__ short Ah[128 * 32];
    __shared__ short Bh[128 * 32];
    __shared__ float rmx[128][2];
    const int t = threadIdx.x, lane = t & 63, wave = t >> 6;
    const int wr = wave >> 1, wc = wave & 1;
    const int row0 = blockIdx.x * 128;
    const int by = blockIdx.y;
    const int col0 = by * 128;
    const int l_row = lane >> 2, l_col = (lane & 3) << 3;
    f32x4 acc[4][4];
    #pragma unroll
    for (int m = 0; m < 4; ++m)
        #pragma unroll
        for (int n = 0; n < 4; ++n) { f32x4 z = {0.f, 0.f, 0.f, 0.f}; acc[m][n] = z; }
    for (int k0 = 0; k0 < 512; k0 += 32) {
        #pragma unroll
        for (int sub = 0; sub < 2; ++sub) {
            int s = wave * 2 + sub;
            int gr = s * 16 + l_row;
            size_t ga = (size_t)(row0 + gr) * 512 + k0 + l_col;
            size_t gb = (size_t)(col0 + gr) * 512 + k0 + l_col;
            gl16(&Ah[s * 512], xh + ga);
            gl16(&Bh[s * 512], Wch + gb);
        }
        __syncthreads();
        bf16x8 bh[4];
        #pragma unroll
        for (int n = 0; n < 4; ++n) bh[n] = ld_frag(Bh, wc * 64 + n * 16, 0, 32);
        #pragma unroll
        for (int m = 0; m < 4; ++m) {
            bf16x8 ah = ld_frag(Ah, wr * 64 + m * 16, 0, 32);
            #pragma unroll
            for (int n = 0; n < 4; ++n) acc[m][n] = MFMA16(ah, bh[n], acc[m][n]);
        }
        __syncthreads();
    }
    if (by < 4) {
        // k ssq: head = by*2+wc, per-wave 64 cols = 1 head
        const int head = by * 2 + wc;
        #pragma unroll
        for (int m = 0; m < 4; ++m)
            #pragma unroll
            for (int i = 0; i < 4; ++i) {
                float s = 0.f;
                #pragma unroll
                for (int n = 0; n < 4; ++n) { float v2 = acc[m][n][i]; s += v2 * v2; }
                s += __shfl_xor(s, 1); s += __shfl_xor(s, 2);
                s += __shfl_xor(s, 4); s += __shfl_xor(s, 8);
                if ((lane & 15) == 0) {
                    int row = row0 + wr * 64 + m * 16 + ((lane >> 4) << 2) + i;
                    int b = row >> 11, nn = row & 2047;
                    ssqbuf[(b * 8 + head) * 2048 + nn] = s;
                }
            }
    } else if (by < 8) {
        #pragma unroll
        for (int m = 0; m < 4; ++m)
            #pragma unroll
            for (int n = 0; n < 4; ++n)
                #pragma unroll
                for (int i = 0; i < 4; ++i) {
                    int row = row0 + wr * 64 + m * 16 + ((lane >> 4) << 2) + i;
                    int gc = col0 + wc * 64 + n * 16 + (lane & 15);
                    int c = gc - 512, h = c >> 6, d = c & 63;
                    int b = row >> 11, nn = row & 2047;
                    vbf[((size_t)(b * 8 + h) * 2048 + nn) * 64 + d] = f2bf(acc[m][n][i]);
                }
    } else {
        const bool isq = (by < 16);
        const int h = isq ? (by - 8) : (by - 16);
        // full-row max: per-wave 64-col max -> LDS exchange across wc
        #pragma unroll
        for (int m = 0; m < 4; ++m)
            #pragma unroll
            for (int i = 0; i < 4; ++i) {
                float mx = fmaxf(fmaxf(acc[m][0][i], acc[m][1][i]),
                                 fmaxf(acc[m][2][i], acc[m][3][i]));
                mx = fmaxf(mx, __shfl_xor(mx, 1));
                mx = fmaxf(mx, __shfl_xor(mx, 2));
                mx = fmaxf(mx, __shfl_xor(mx, 4));
                mx = fmaxf(mx, __shfl_xor(mx, 8));
                if ((lane & 15) == 0)
                    rmx[wr * 64 + m * 16 + ((lane >> 4) << 2) + i][wc] = mx;
            }
        __syncthreads();
        short* dst = isq ? phiq : pkloc;
        #pragma unroll
        for (int m = 0; m < 4; ++m)
            #pragma unroll
            for (int i = 0; i < 4; ++i) {
                int lr = wr * 64 + m * 16 + ((lane >> 4) << 2) + i;
                float fm = fmaxf(rmx[lr][0], rmx[lr][1]);
                int row = row0 + lr;
                int b = row >> 11, nn = row & 2047;
                size_t g = (size_t)(b * 8 + h) * 2048 + nn;
                #pragma unroll
                for (int n = 0; n < 4; ++n) {
                    int mc = wc * 64 + n * 16 + (lane & 15);
                    float e = __expf(acc[m][n][i] - fm);
                    float val = isq ? (e * INV_SQRT_M + 1e-4f) : e;
                    dst[g * 128 + mc] = f2bf(val);
                }
                if (!isq && wc == 0 && (lane & 15) == 0) pmaxp[g] = fm;
            }
    }
}

// ---------------- global key-max: 32 blocks, 32 atomics ----------------
__global__ __launch_bounds__(256) void kmax_reduce(const float* __restrict__ pmaxp,
    const float* __restrict__ ssqbuf, unsigned* __restrict__ gmaxu)
{
    float m = -3.402823466e38f;
    for (int g = blockIdx.x * 256 + threadIdx.x; g < 32768; g += 8192)
        m = fmaxf(m, pmaxp[g] - 0.5f * ssqbuf[g]);
    #pragma unroll
    for (int off = 1; off < 64; off <<= 1) m = fmaxf(m, __shfl_xor(m, off));
    __shared__ float w[4];
    if ((threadIdx.x & 63) == 0) w[threadIdx.x >> 6] = m;
    __syncthreads();
    if (threadIdx.x == 0)
        atomicMax(gmaxu, encf(fmaxf(fmaxf(w[0], w[1]), fmaxf(w[2], w[3]))));
}

// ---------------- per-chunk KV sums: ST[d][m] = sum_n v[n][d] pk[n][m] (bf16 out) ----------------
// pk and v staged TRANSPOSED in LDS so all MFMA fragment loads are contiguous ds_read_b128
__global__ __launch_bounds__(256) void chunk_kv_mfma(
    const short* __restrict__ pkloc, const float* __restrict__ ssqbuf,
    const float* __restrict__ pmaxp, const unsigned* __restrict__ gmaxu,
    const short* __restrict__ v_bf, short* __restrict__ Sbf, float* __restrict__ ksum)
{
    __shared__ short pk_T[128][66];   // [m][n]
    __shared__ short v_T[64][66];     // [d][n]
    __shared__ float srow[64];
    const int t = threadIdx.x, lane = t & 63, wave = t >> 6;
    const int wr = wave >> 1, wc = wave & 1;
    const int bh = blockIdx.x >> 5, j = blockIdx.x & 31;
    const int n0 = j << 6;
    const float g = decf(gmaxu[0]);
    if (t < 64) {
        int gr = bh * 2048 + n0 + t;
        srow[t] = __expf(pmaxp[gr] - 0.5f * ssqbuf[gr] - g) * INV_SQRT_M;
    }
    __syncthreads();
    #pragma unroll
    for (int it = 0; it < 4; ++it) {
        int idx = t + it * 256;
        int r = idx >> 4, c8 = (idx & 15) << 3;
        bf16x8 raw = *(const bf16x8*)(pkloc + ((size_t)(bh * 2048 + n0 + r)) * 128 + c8);
        float s = srow[r];
        #pragma unroll
        for (int u = 0; u < 8; ++u) pk_T[c8 + u][r] = f2bf(bf2f(raw[u]) * s + 1e-4f);
    }
    #pragma unroll
    for (int it = 0; it < 2; ++it) {
        int idx = t + it * 256;
        int r = idx >> 3, c8 = (idx & 7) << 3;
        bf16x8 raw = *(const bf16x8*)(v_bf + ((size_t)(bh * 2048 + n0 + r)) * 64 + c8);
        #pragma unroll
        for (int u = 0; u < 8; ++u) v_T[c8 + u][r] = raw[u];
    }
    __syncthreads();
    f32x4 acc[2][4];
    #pragma unroll
    for (int mi = 0; mi < 2; ++mi)
        #pragma unroll
        for (int ni = 0; ni < 4; ++ni) { f32x4 z = {0.f, 0.f, 0.f, 0.f}; acc[mi][ni] = z; }
    #pragma unroll
    for (int ks = 0; ks < 2; ++ks) {
        bf16x8 a0 = ld_frag(&v_T[0][0], wr * 32, ks * 32, 66);
        bf16x8 a1 = ld_frag(&v_T[0][0], wr * 32 + 16, ks * 32, 66);
        #pragma unroll
        for (int ni = 0; ni < 4; ++ni) {
            bf16x8 bb = ld_frag(&pk_T[0][0], wc * 64 + ni * 16, ks * 32, 66);
            acc[0][ni] = MFMA16(a0, bb, acc[0][ni]);
            acc[1][ni] = MFMA16(a1, bb, acc[1][ni]);
        }
    }
    const size_t sbase = ((size_t)blockIdx.x) << 13;
    #pragma unroll
    for (int mi = 0; mi < 2; ++mi)
        #pragma unroll
        for (int ni = 0; ni < 4; ++ni)
            #pragma unroll
            for (int i = 0; i < 4; ++i) {
                int row = wr * 32 + mi * 16 + ((lane >> 4) << 2) + i;
                int col = wc * 64 + ni * 16 + (lane & 15);
                Sbf[sbase + (size_t)row * 128 + col] = f2bf(acc[mi][ni][i]);
            }
    if (t < 128) {
        float s = 0.f;
        #pragma unroll
        for (int n8 = 0; n8 < 64; n8 += 8) {
            bf16x8 v = *(const bf16x8*)&pk_T[t][n8];
            #pragma unroll
            for (int u = 0; u < 8; ++u) s += bf2f(v[u]);
        }
        ksum[((size_t)blockIdx.x) * 128 + t] = s;
    }
}

// ---------------- exclusive prefix over chunks (vectorized bf16x8 / float4) ----------------
__global__ __launch_bounds__(256) void prefix_scan(const short* __restrict__ Sbf,
    const float* __restrict__ ksum, short* __restrict__ STbf, float* __restrict__ kpre)
{
    const int bh = blockIdx.x, y = blockIdx.y, t = threadIdx.x;
    if (y < 4) {
        int e8 = (y * 256 + t) * 8;   // within 8192-elem chunk
        size_t base = (size_t)bh * NC_ * 8192 + e8;
        float run[8] = {0.f, 0.f, 0.f, 0.f, 0.f, 0.f, 0.f, 0.f};
        #pragma unroll
        for (int j = 0; j < NC_; ++j) {
            bf16x8 v = *(const bf16x8*)(Sbf + base + (size_t)j * 8192);
            bf16x8 o;
            #pragma unroll
            for (int u = 0; u < 8; ++u) { o[u] = f2bf(run[u]); run[u] += bf2f(v[u]); }
            *(bf16x8*)(STbf + base + (size_t)j * 8192) = o;
        }
    } else if (t < 32) {
        size_t base = (size_t)bh * NC_ * 128 + t * 4;
        float r0 = 0.f, r1 = 0.f, r2 = 0.f, r3 = 0.f;
        #pragma unroll
        for (int j = 0; j < NC_; ++j) {
            float4 v = *(const float4*)(ksum + base + (size_t)j * 128);
            float4 o; o.x = r0; o.y = r1; o.z = r2; o.w = r3;
            *(float4*)(kpre + base + (size_t)j * 128) = o;
            r0 += v.x; r1 += v.y; r2 += v.z; r3 += v.w;
        }
    }
}

// ---------------- per-chunk output (MFMA); o written bf16 (no lo split) ----------------
__global__ __launch_bounds__(256) void chunk_out_mfma(
    const short* __restrict__ phi_q, const short* __restrict__ pkloc,
    const float* __restrict__ ssqbuf, const float* __restrict__ pmaxp,
    const unsigned* __restrict__ gmaxu,
    const short* __restrict__ v_bf, const short* __restrict__ STbf,
    const float* __restrict__ kpre, short* __restrict__ o_bf)
{
    __shared__ short pq_l[64][136];
    __shared__ short pkst_l[64][136];
    __shared__ short v_T[64][66];     // [d][n]
    __shared__ short a_l[64][72];
    __shared__ float rsum[64][8];
    __shared__ float den[64];
    __shared__ float ksp_l[128];
    __shared__ float srow[64];
    const int t = threadIdx.x, lane = t & 63, wave = t >> 6;
    const int wr = wave >> 1, wc = wave & 1;
    const int bh = blockIdx.x >> 5, j = blockIdx.x & 31;
    const int n0 = j << 6;
    const size_t prow = (size_t)bh * N_ + n0;
    const float g = decf(gmaxu[0]);
    if (t < 64) {
        int gr = bh * 2048 + n0 + t;
        srow[t] = __expf(pmaxp[gr] - 0.5f * ssqbuf[gr] - g) * INV_SQRT_M;
    }
    if (t < 128) ksp_l[t] = kpre[((size_t)bh * NC_ + j) * 128 + t];
    __syncthreads();
    #pragma unroll
    for (int it = 0; it < 4; ++it) {
        int idx = t + it * 256;
        int r = idx >> 4, c8 = (idx & 15) << 3;
        *(bf16x8*)&pq_l[r][c8] = *(const bf16x8*)(phi_q + (prow + r) * 128 + c8);
        bf16x8 raw = *(const bf16x8*)(pkloc + (prow + r) * 128 + c8);
        float s = srow[r];
        bf16x8 o;
        #pragma unroll
        for (int u = 0; u < 8; ++u) o[u] = f2bf(bf2f(raw[u]) * s + 1e-4f);
        *(bf16x8*)&pkst_l[r][c8] = o;
    }
    #pragma unroll
    for (int it = 0; it < 2; ++it) {
        int idx = t + it * 256;
        int r = idx >> 3, c8 = (idx & 7) << 3;
        bf16x8 raw = *(const bf16x8*)(v_bf + (prow + r) * 64 + c8);
        #pragma unroll
        for (int u = 0; u < 8; ++u) v_T[c8 + u][r] = raw[u];
    }
    __syncthreads();
    f32x4 qk[2][2];
    #pragma unroll
    for (int mi = 0; mi < 2; ++mi)
        #pragma unroll
        for (int ni = 0; ni < 2; ++ni) { f32x4 z = {0.f, 0.f, 0.f, 0.f}; qk[mi][ni] = z; }
    #pragma unroll
    for (int ks = 0; ks < 4; ++ks) {
        bf16x8 a0 = ld_frag(&pq_l[0][0], wr * 32, ks * 32, 136);
        bf16x8 a1 = ld_frag(&pq_l[0][0], wr * 32 + 16, ks * 32, 136);
        bf16x8 b0 = ld_frag(&pkst_l[0][0], wc * 32, ks * 32, 136);
        bf16x8 b1 = ld_frag(&pkst_l[0][0], wc * 32 + 16, ks * 32, 136);
        qk[0][0] = MFMA16(a0, b0, qk[0][0]);
        qk[0][1] = MFMA16(a0, b1, qk[0][1]);
        qk[1][0] = MFMA16(a1, b0, qk[1][0]);
        qk[1][1] = MFMA16(a1, b1, qk[1][1]);
    }
    #pragma unroll
    for (int mi = 0; mi < 2; ++mi)
        #pragma unroll
        for (int i = 0; i < 4; ++i) {
            int row = wr * 32 + mi * 16 + ((lane >> 4) << 2) + i;
            float part = 0.f;
            #pragma unroll
            for (int ni = 0; ni < 2; ++ni) {
                int col = wc * 32 + ni * 16 + (lane & 15);
                float val = (col <= row) ? qk[mi][ni][i] : 0.f;
                a_l[row][col] = f2bf(val);
                part += val;
            }
            part += __shfl_xor(part, 1);
            part += __shfl_xor(part, 2);
            part += __shfl_xor(part, 4);
            part += __shfl_xor(part, 8);
            if ((lane & 15) == 0) rsum[row][wc] = part;
        }
    {
        int row = t & 63, qq = t >> 6;
        float s = 0.f;
        #pragma unroll
        for (int m = 0; m < 32; ++m) s += bf2f(pq_l[row][qq * 32 + m]) * ksp_l[qq * 32 + m];
        rsum[row][4 + qq] = s;
    }
    __syncthreads();
    #pragma unroll
    for (int it = 0; it < 4; ++it) {
        int idx = t + it * 256;
        int r = idx >> 4, c8 = (idx & 15) << 3;
        *(bf16x8*)&pkst_l[r][c8] =
            *(const bf16x8*)(STbf + (((size_t)bh * NC_ + j) << 13) + r * 128 + c8);
    }
    if (t < 64) {
        float s = rsum[t][0] + rsum[t][1] + rsum[t][4] + rsum[t][5] + rsum[t][6] + rsum[t][7];
        den[t] = 1.0f / (s + 1e-6f);
    }
    __syncthreads();
    f32x4 oa[2][2];
    #pragma unroll
    for (int mi = 0; mi < 2; ++mi)
        #pragma unroll
        for (int ni = 0; ni < 2; ++ni) { f32x4 z = {0.f, 0.f, 0.f, 0.f}; oa[mi][ni] = z; }
    #pragma unroll
    for (int ks = 0; ks < 2; ++ks) {
        bf16x8 a0 = ld_frag(&a_l[0][0], wr * 32, ks * 32, 72);
        bf16x8 a1 = ld_frag(&a_l[0][0], wr * 32 + 16, ks * 32, 72);
        #pragma unroll
        for (int ni = 0; ni < 2; ++ni) {
            bf16x8 bb = ld_frag(&v_T[0][0], wc * 32 + ni * 16, ks * 32, 66);
            oa[0][ni] = MFMA16(a0, bb, oa[0][ni]);
            oa[1][ni] = MFMA16(a1, bb, oa[1][ni]);
        }
    }
    #pragma unroll
    for (int ks = 0; ks < 4; ++ks) {
        bf16x8 a0 = ld_frag(&pq_l[0][0], wr * 32, ks * 32, 136);
        bf16x8 a1 = ld_frag(&pq_l[0][0], wr * 32 + 16, ks * 32, 136);
        #pragma unroll
        for (int ni = 0; ni < 2; ++ni) {
            bf16x8 bb = ld_frag(&pkst_l[0][0], wc * 32 + ni * 16, ks * 32, 136);
            oa[0][ni] = MFMA16(a0, bb, oa[0][ni]);
            oa[1][ni] = MFMA16(a1, bb, oa[1][ni]);
        }
    }
    const int b_ = bh >> 3, h = bh & 7;
    #pragma unroll
    for (int mi = 0; mi < 2; ++mi)
        #pragma unroll
        for (int ni = 0; ni < 2; ++ni)
            #pragma unroll
            for (int i = 0; i < 4; ++i) {
                int row = wr * 32 + mi * 16 + ((lane >> 4) << 2) + i;
                int col = wc * 32 + ni * 16 + (lane & 15);
                float val = oa[mi][ni][i] * den[row];
                size_t oi = ((size_t)b_ * N_ + n0 + row) * 512 + h * 64 + col;
                o_bf[oi] = f2bf(val);
            }
}

// ---------------- output projection: out = o @ Woh^T + bo; 128x64 tiles, 8 waves ----------------
__global__ __launch_bounds__(512) void gemm_out(
    const short* __restrict__ o_bf, const short* __restrict__ Woh,
    const float* __restrict__ bo, float* __restrict__ out)
{
    __shared__ short Ah[128 * 32];
    __shared__ short Bh[64 * 32];
    const int t = threadIdx.x, lane = t & 63, wave = t >> 6;   // 8 waves
    const int row0 = blockIdx.x * 128, col0 = blockIdx.y * 64;
    const int l_row = lane >> 2, l_col = (lane & 3) << 3;
    f32x4 acc[4];
    #pragma unroll
    for (int n = 0; n < 4; ++n) { f32x4 z = {0.f, 0.f, 0.f, 0.f}; acc[n] = z; }
    for (int k0 = 0; k0 < 512; k0 += 32) {
        {
            int gr = wave * 16 + l_row;
            size_t ga = (size_t)(row0 + gr) * 512 + k0 + l_col;
            gl16(&Ah[wave * 512], o_bf + ga);
        }
        if (wave < 4) {
            int gr = wave * 16 + l_row;
            size_t gb = (size_t)(col0 + gr) * 512 + k0 + l_col;
            gl16(&Bh[wave * 512], Woh + gb);
        }
        __syncthreads();
        bf16x8 ah = ld_frag(Ah, wave * 16, 0, 32);
        #pragma unroll
        for (int n = 0; n < 4; ++n) {
            bf16x8 bh = ld_frag(Bh, n * 16, 0, 32);
            acc[n] = MFMA16(ah, bh, acc[n]);
        }
        __syncthreads();
    }
    #pragma unroll
    for (int n = 0; n < 4; ++n)
        #pragma unroll
        for (int i = 0; i < 4; ++i) {
            int gr = row0 + wave * 16 + ((lane >> 4) << 2) + i;
            int gc = col0 + n * 16 + (lane & 15);
            out[(size_t)gr * 512 + gc] = acc[n][i] + bo[gc];
        }
}

extern "C" void kernel_launch(void* const* d_in, const int* in_sizes, int n_in,
                              void* d_out, int out_size, void* d_ws, size_t ws_size,
                              hipStream_t stream) {
    const float* x     = (const float*)d_in[0];
    const float* omega = (const float*)d_in[1];
    const float* Wq    = (const float*)d_in[2];
    const float* Wk    = (const float*)d_in[3];
    const float* Wv    = (const float*)d_in[4];
    const float* Wo    = (const float*)d_in[5];
    const float* bo    = (const float*)d_in[6];
    float* out = (float*)d_out;

    char* w = (char*)d_ws;
    short* xh   = (short*)(w);                                  // 0..4 MB
    short* Wch  = (short*)(w + (8ull  << 20));                  // 8..11 (3072x512 bf16)
    short* Woh  = (short*)(w + (14ull << 20));                  // 14..14.5
    short* phiq = (short*)(w + (15ull << 20));                  // 15..23
    short* pkloc= (short*)(w + (23ull << 20));                  // 23..31
    short* vbf  = (short*)(w + (31ull << 20));                  // 31..35
    short* Sbf  = (short*)(w + (35ull << 20));                  // 35..43
    short* STbf = (short*)(w + (43ull << 20));                  // 43..51
    short* obf  = (short*)(w + (51ull << 20));                  // 51..55
    float* ssqb = (float*)(w + (59ull << 20));                            // 128 KB
    float* pmaxp= (float*)(w + (59ull << 20) + (128ull << 10));           // 128 KB
    float* ksum = (float*)(w + (59ull << 20) + (256ull << 10));           // 256 KB
    float* kpre = (float*)(w + (59ull << 20) + (512ull << 10));           // 256 KB
    unsigned* gmaxu = (unsigned*)(w + (59ull << 20) + (768ull << 10));    // 4 B

    prep_all<<<2944, 256, 0, stream>>>(x, Wq, Wk, Wv, Wo, omega,
                                       xh, Wch, Woh, gmaxu);
    gemm_fused<<<dim3(32, 24), 256, 0, stream>>>(xh, Wch, phiq, pkloc,
                                                 vbf, ssqb, pmaxp);
    kmax_reduce<<<32, 256, 0, stream>>>(pmaxp, ssqb, gmaxu);
    chunk_kv_mfma<<<512, 256, 0, stream>>>(pkloc, ssqb, pmaxp, gmaxu, vbf, Sbf, ksum);
    prefix_scan<<<dim3(16, 5), 256, 0, stream>>>(Sbf, ksum, STbf, kpre);
    chunk_out_mfma<<<512, 256, 0, stream>>>(phiq, pkloc, ssqb, pmaxp, gmaxu,
                                            vbf, STbf, kpre, obf);
    gemm_out<<<dim3(32, 8), 512, 0, stream>>>(obf, Woh, bo, out);
}